// Round 1
// baseline (9000.175 us; speedup 1.0000x reference)
//
#include <hip/hip_runtime.h>
#include <hip/hip_bf16.h>
#include <math.h>

// Problem constants
#define BATCH 32
#define SEQ   1024
#define NS    4        // n streams
#define DIM   192      // d per stream
#define ND    768      // n*d
#define NH    3        // attention heads
#define HD    64       // head dim
#define MLP   768
#define TOKENS (BATCH*SEQ)   // 32768

__device__ inline float gelu_tanh(float x) {
    float x3 = x * x * x;
    return 0.5f * x * (1.0f + tanhf(0.7978845608028654f * (x + 0.044715f * x3)));
}

// ---------------------------------------------------------------------------
// Kernel 1: per-token gating. One wave (64 threads) per token.
//  - RMSNorm(x[token], 768) -> streams
//  - 24 dot products vs phi_pre/phi_post/phi_res
//  - sigmoid / 2*sigmoid / sinkhorn(4x4, 20 iters)
//  - x_res -> d_out (overwrite), x_in -> xin, LN1(x_in) -> hbuf, h_post -> hpost
// ---------------------------------------------------------------------------
__global__ __launch_bounds__(64) void gating_kernel(
    const float* __restrict__ x, const float* __restrict__ norm_w,
    const float* __restrict__ phi_pre, const float* __restrict__ phi_post,
    const float* __restrict__ phi_res, const float* __restrict__ b_pre,
    const float* __restrict__ b_post, const float* __restrict__ b_res,
    const float* __restrict__ alpha_pre, const float* __restrict__ alpha_post,
    const float* __restrict__ alpha_res,
    const float* __restrict__ ln1_w, const float* __restrict__ ln1_b,
    float* __restrict__ out, float* __restrict__ xin,
    float* __restrict__ hbuf, float* __restrict__ hpost)
{
    const int token = blockIdx.x;
    const int lane  = threadIdx.x;
    const float* xt = x + (size_t)token * ND;

    __shared__ float ldsx[ND];

    // load 12 floats per lane as 3 float4
    float4 xv[3];
#pragma unroll
    for (int r = 0; r < 3; r++) {
        xv[r] = ((const float4*)xt)[lane + 64 * r];
        ((float4*)ldsx)[lane + 64 * r] = xv[r];
    }

    // sum of squares
    float ssq = 0.f;
#pragma unroll
    for (int r = 0; r < 3; r++)
        ssq += xv[r].x*xv[r].x + xv[r].y*xv[r].y + xv[r].z*xv[r].z + xv[r].w*xv[r].w;
#pragma unroll
    for (int off = 32; off; off >>= 1) ssq += __shfl_xor(ssq, off);
    const float rinv = rsqrtf(ssq / (float)ND + 1e-8f);  // 1/rms

    // 24 dot products (4 pre, 4 post, 16 res)
    float acc[24];
#pragma unroll
    for (int p = 0; p < 24; p++) acc[p] = 0.f;

#pragma unroll
    for (int r = 0; r < 3; r++) {
        const int g = lane + 64 * r;
        const float4 wv = ((const float4*)norm_w)[g];
        float s[4];
        s[0] = xv[r].x * wv.x * rinv;
        s[1] = xv[r].y * wv.y * rinv;
        s[2] = xv[r].z * wv.z * rinv;
        s[3] = xv[r].w * wv.w * rinv;
#pragma unroll
        for (int e = 0; e < 4; e++) {
            const int j = 4 * g + e;
            const float sj = s[e];
            const float* pp = phi_pre + (size_t)j * 4;
#pragma unroll
            for (int p = 0; p < 4; p++) acc[p] += sj * pp[p];
            const float* po = phi_post + (size_t)j * 4;
#pragma unroll
            for (int p = 0; p < 4; p++) acc[4 + p] += sj * po[p];
            const float* pr = phi_res + (size_t)j * 16;
#pragma unroll
            for (int p = 0; p < 16; p++) acc[8 + p] += sj * pr[p];
        }
    }
    // butterfly reduce -> all lanes hold totals
#pragma unroll
    for (int p = 0; p < 24; p++) {
#pragma unroll
        for (int off = 32; off; off >>= 1) acc[p] += __shfl_xor(acc[p], off);
    }

    const float apre = alpha_pre[0], apost = alpha_post[0], ares = alpha_res[0];
    float hpre[NS], hpo[NS], hres[NS * NS];
#pragma unroll
    for (int i = 0; i < NS; i++) {
        hpre[i] = 1.0f / (1.0f + expf(-(apre * acc[i] + b_pre[i])));
        hpo[i]  = 2.0f / (1.0f + expf(-(apost * acc[4 + i] + b_post[i])));
    }
#pragma unroll
    for (int p = 0; p < NS * NS; p++) hres[p] = ares * acc[8 + p] + b_res[p];

    // sinkhorn: global max-shift, exp, 20 alternating row/col normalizations
    float gmax = hres[0];
#pragma unroll
    for (int p = 1; p < 16; p++) gmax = fmaxf(gmax, hres[p]);
#pragma unroll
    for (int p = 0; p < 16; p++) hres[p] = expf(hres[p] - gmax);
    for (int it = 0; it < 20; it++) {
#pragma unroll
        for (int i = 0; i < NS; i++) {
            float rs = hres[i*4+0] + hres[i*4+1] + hres[i*4+2] + hres[i*4+3];
            float inv = 1.0f / (rs + 1e-8f);
#pragma unroll
            for (int j = 0; j < NS; j++) hres[i*4+j] *= inv;
        }
#pragma unroll
        for (int j = 0; j < NS; j++) {
            float cs = hres[0*4+j] + hres[1*4+j] + hres[2*4+j] + hres[3*4+j];
            float inv = 1.0f / (cs + 1e-8f);
#pragma unroll
            for (int i = 0; i < NS; i++) hres[i*4+j] *= inv;
        }
    }

    __syncthreads();  // ldsx fully written

    // x_res[i][dd] = sum_j hres[i][j] * x[j][dd]  -> overwrite d_out
    float* ot = out + (size_t)token * ND;
#pragma unroll
    for (int r = 0; r < 3; r++) {
        const int g  = lane + 64 * r;   // float4 index within token
        const int p0 = 4 * g;
        const int i  = p0 / DIM;
        const int d0 = p0 % DIM;
        float4 o;
        o.x = hres[i*4+0]*ldsx[0*DIM+d0+0] + hres[i*4+1]*ldsx[1*DIM+d0+0]
            + hres[i*4+2]*ldsx[2*DIM+d0+0] + hres[i*4+3]*ldsx[3*DIM+d0+0];
        o.y = hres[i*4+0]*ldsx[0*DIM+d0+1] + hres[i*4+1]*ldsx[1*DIM+d0+1]
            + hres[i*4+2]*ldsx[2*DIM+d0+1] + hres[i*4+3]*ldsx[3*DIM+d0+1];
        o.z = hres[i*4+0]*ldsx[0*DIM+d0+2] + hres[i*4+1]*ldsx[1*DIM+d0+2]
            + hres[i*4+2]*ldsx[2*DIM+d0+2] + hres[i*4+3]*ldsx[3*DIM+d0+2];
        o.w = hres[i*4+0]*ldsx[0*DIM+d0+3] + hres[i*4+1]*ldsx[1*DIM+d0+3]
            + hres[i*4+2]*ldsx[2*DIM+d0+3] + hres[i*4+3]*ldsx[3*DIM+d0+3];
        ((float4*)ot)[g] = o;
    }

    // x_in[d] = sum_j hpre[j] * x[j][d]; then LN1
    float xi[3];
#pragma unroll
    for (int r = 0; r < 3; r++) {
        const int d = lane + 64 * r;
        xi[r] = hpre[0]*ldsx[d] + hpre[1]*ldsx[DIM+d]
              + hpre[2]*ldsx[2*DIM+d] + hpre[3]*ldsx[3*DIM+d];
    }
    float sum = xi[0] + xi[1] + xi[2];
#pragma unroll
    for (int off = 32; off; off >>= 1) sum += __shfl_xor(sum, off);
    const float mean = sum / (float)DIM;
    float vs = (xi[0]-mean)*(xi[0]-mean) + (xi[1]-mean)*(xi[1]-mean) + (xi[2]-mean)*(xi[2]-mean);
#pragma unroll
    for (int off = 32; off; off >>= 1) vs += __shfl_xor(vs, off);
    const float inv = rsqrtf(vs / (float)DIM + 1e-5f);

    float* xint = xin  + (size_t)token * DIM;
    float* ht   = hbuf + (size_t)token * DIM;
#pragma unroll
    for (int r = 0; r < 3; r++) {
        const int d = lane + 64 * r;
        xint[d] = xi[r];
        ht[d]   = (xi[r] - mean) * inv * ln1_w[d] + ln1_b[d];
    }
    if (lane < NS) hpost[(size_t)token * NS + lane] = hpo[lane];
}

// ---------------------------------------------------------------------------
// Tiled fp32 GEMM: C[M,N] = op(A[M,K] @ B[K,N] [+ R]).  OP: 0 plain, 1 +R, 2 gelu
// 64x64 tile, TK=16, 256 threads, 4x4 microtile. M,N mult of 64; K mult of 16.
// ---------------------------------------------------------------------------
template<int OP>
__global__ __launch_bounds__(256) void gemm_kernel(
    const float* __restrict__ A, const float* __restrict__ Bm,
    const float* __restrict__ R, float* __restrict__ C,
    int M, int N, int K)
{
    __shared__ float As[16][64 + 4];
    __shared__ float Bs[16][64 + 4];
    const int tx = threadIdx.x;            // 0..15
    const int ty = threadIdx.y;            // 0..15
    const int l  = ty * 16 + tx;           // 0..255
    const int m0 = blockIdx.y * 64;
    const int n0 = blockIdx.x * 64;

    float c[4][4];
#pragma unroll
    for (int i = 0; i < 4; i++)
#pragma unroll
        for (int j = 0; j < 4; j++) c[i][j] = 0.f;

    for (int k0 = 0; k0 < K; k0 += 16) {
        {   // A tile: 64 rows x 16 k
            const int row = l >> 2, kq = (l & 3) * 4;
            const float4 a = *(const float4*)(A + (size_t)(m0 + row) * K + k0 + kq);
            As[kq+0][row] = a.x; As[kq+1][row] = a.y;
            As[kq+2][row] = a.z; As[kq+3][row] = a.w;
        }
        {   // B tile: 16 k x 64 cols
            const int kr = l >> 4, nq = (l & 15) * 4;
            const float4 b = *(const float4*)(Bm + (size_t)(k0 + kr) * N + n0 + nq);
            Bs[kr][nq+0] = b.x; Bs[kr][nq+1] = b.y;
            Bs[kr][nq+2] = b.z; Bs[kr][nq+3] = b.w;
        }
        __syncthreads();
#pragma unroll
        for (int kk = 0; kk < 16; kk++) {
            float a[4], b[4];
#pragma unroll
            for (int i = 0; i < 4; i++) a[i] = As[kk][ty * 4 + i];
#pragma unroll
            for (int j = 0; j < 4; j++) b[j] = Bs[kk][tx * 4 + j];
#pragma unroll
            for (int i = 0; i < 4; i++)
#pragma unroll
                for (int j = 0; j < 4; j++) c[i][j] += a[i] * b[j];
        }
        __syncthreads();
    }

#pragma unroll
    for (int i = 0; i < 4; i++) {
        const int row = m0 + ty * 4 + i;
        const size_t base = (size_t)row * N + n0 + tx * 4;
#pragma unroll
        for (int j = 0; j < 4; j++) {
            float v = c[i][j];
            if (OP == 1) v += R[base + j];
            if (OP == 2) v = gelu_tanh(v);
            C[base + j] = v;
        }
    }
}

// ---------------------------------------------------------------------------
// Attention: one block per (q, b*h). 256 threads.
//  scores row (1024) in LDS, softmax, then p @ V.
// q,k,v layout: [token, h*64+d]
// ---------------------------------------------------------------------------
__global__ __launch_bounds__(256) void attn_kernel(
    const float* __restrict__ Q, const float* __restrict__ Kb,
    const float* __restrict__ V, float* __restrict__ O)
{
    const int q  = blockIdx.x;       // 0..1023
    const int bh = blockIdx.y;       // 0..95
    const int b  = bh / NH, h = bh % NH;
    const int tid = threadIdx.x;

    __shared__ float qs[HD];
    __shared__ float sc[SEQ];
    __shared__ float red[256];

    const size_t tokq = (size_t)(b * SEQ + q);
    if (tid < HD) qs[tid] = Q[tokq * DIM + h * HD + tid];
    __syncthreads();

    // phase 1: scores
    float myS[4];
    float smax = -1e30f;
#pragma unroll
    for (int c = 0; c < 4; c++) {
        const int kk = tid + 256 * c;
        const float4* kr = (const float4*)(Kb + (size_t)(b * SEQ + kk) * DIM + h * HD);
        const float4* qv = (const float4*)qs;
        float d = 0.f;
#pragma unroll
        for (int e = 0; e < 16; e++) {
            float4 kv = kr[e], qq = qv[e];
            d += kv.x*qq.x + kv.y*qq.y + kv.z*qq.z + kv.w*qq.w;
        }
        d *= 0.125f;   // 1/sqrt(64)
        myS[c] = d;
        smax = fmaxf(smax, d);
    }
    red[tid] = smax; __syncthreads();
    for (int s = 128; s; s >>= 1) {
        if (tid < s) red[tid] = fmaxf(red[tid], red[tid + s]);
        __syncthreads();
    }
    const float m = red[0];
    __syncthreads();

    float lsum = 0.f;
#pragma unroll
    for (int c = 0; c < 4; c++) {
        float p = expf(myS[c] - m);
        sc[tid + 256 * c] = p;
        lsum += p;
    }
    red[tid] = lsum; __syncthreads();
    for (int s = 128; s; s >>= 1) {
        if (tid < s) red[tid] += red[tid + s];
        __syncthreads();
    }
    const float inv = 1.0f / red[0];
    __syncthreads();

    // phase 2: out[d] = inv * sum_k p[k] * V[k][d]
    const int d = tid & 63, c = tid >> 6;
    float acc = 0.f;
    const int k0 = c * 256;
    for (int kk = k0; kk < k0 + 256; kk++) {
        acc += sc[kk] * V[(size_t)(b * SEQ + kk) * DIM + h * HD + d];
    }
    red[tid] = acc;   // tid == c*64 + d
    __syncthreads();
    if (tid < HD) {
        float o = (red[tid] + red[64 + tid] + red[128 + tid] + red[192 + tid]) * inv;
        O[tokq * DIM + h * HD + tid] = o;
    }
}

// ---------------------------------------------------------------------------
// LayerNorm over 192, one wave per token
// ---------------------------------------------------------------------------
__global__ __launch_bounds__(64) void ln_kernel(
    const float* __restrict__ X, const float* __restrict__ w,
    const float* __restrict__ bb, float* __restrict__ Y)
{
    const int token = blockIdx.x;
    const int lane  = threadIdx.x;
    const float* xt = X + (size_t)token * DIM;
    float v[3];
#pragma unroll
    for (int r = 0; r < 3; r++) v[r] = xt[lane + 64 * r];
    float sum = v[0] + v[1] + v[2];
#pragma unroll
    for (int off = 32; off; off >>= 1) sum += __shfl_xor(sum, off);
    const float mean = sum / (float)DIM;
    float vs = (v[0]-mean)*(v[0]-mean) + (v[1]-mean)*(v[1]-mean) + (v[2]-mean)*(v[2]-mean);
#pragma unroll
    for (int off = 32; off; off >>= 1) vs += __shfl_xor(vs, off);
    const float inv = rsqrtf(vs / (float)DIM + 1e-5f);
    float* yt = Y + (size_t)token * DIM;
#pragma unroll
    for (int r = 0; r < 3; r++) {
        const int d = lane + 64 * r;
        yt[d] = (v[r] - mean) * inv * w[d] + bb[d];
    }
}

// ---------------------------------------------------------------------------
// Final: out[token, i, d] += y[token, d] * hpost[token, i]
// ---------------------------------------------------------------------------
__global__ __launch_bounds__(256) void final_kernel(
    const float* __restrict__ y, const float* __restrict__ hpost,
    float* __restrict__ out)
{
    const size_t g = (size_t)blockIdx.x * blockDim.x + threadIdx.x;  // float4 idx
    if (g >= (size_t)TOKENS * (ND / 4)) return;
    const int token = (int)(g / (ND / 4));
    const int f     = (int)(g % (ND / 4));   // 0..191 (float4 within token)
    const int i     = f / (DIM / 4);         // stream index
    const int d4    = f % (DIM / 4);
    const float4 yv = ((const float4*)(y + (size_t)token * DIM))[d4];
    const float hp  = hpost[(size_t)token * NS + i];
    float4* op = (float4*)out + g;
    float4 ov = *op;
    ov.x += yv.x * hp; ov.y += yv.y * hp; ov.z += yv.z * hp; ov.w += yv.w * hp;
    *op = ov;
}

// ---------------------------------------------------------------------------
extern "C" void kernel_launch(void* const* d_in, const int* in_sizes, int n_in,
                              void* d_out, int out_size, void* d_ws, size_t ws_size,
                              hipStream_t stream) {
    const float* x         = (const float*)d_in[0];
    const float* norm_w    = (const float*)d_in[1];
    const float* phi_pre   = (const float*)d_in[2];
    const float* phi_post  = (const float*)d_in[3];
    const float* phi_res   = (const float*)d_in[4];
    const float* b_pre     = (const float*)d_in[5];
    const float* b_post    = (const float*)d_in[6];
    const float* b_res     = (const float*)d_in[7];
    const float* alpha_pre = (const float*)d_in[8];
    const float* alpha_post= (const float*)d_in[9];
    const float* alpha_res = (const float*)d_in[10];
    const float* ln1_w     = (const float*)d_in[11];
    const float* ln1_b     = (const float*)d_in[12];
    const float* Wq        = (const float*)d_in[13];
    const float* Wk        = (const float*)d_in[14];
    const float* Wv        = (const float*)d_in[15];
    const float* Wo        = (const float*)d_in[16];
    const float* ln2_w     = (const float*)d_in[17];
    const float* ln2_b     = (const float*)d_in[18];
    const float* W1        = (const float*)d_in[19];
    const float* W2        = (const float*)d_in[20];

    float* out = (float*)d_out;
    float* ws  = (float*)d_ws;

    const size_t TB = (size_t)TOKENS * DIM;      // 6,291,456 per token-buffer
    float* xin   = ws;                           // x_in -> later h2 -> later y
    float* hbuf  = ws + TB;                      // LN1(x_in) -> later x1
    float* cbuf  = ws + 2 * TB;                  // attn_out; g starts here
    float* qbuf  = ws + 3 * TB;
    float* kbuf  = ws + 4 * TB;
    float* vbuf  = ws + 5 * TB;
    float* hpost = ws + 6 * TB;                  // TOKENS*4
    float* gbuf  = cbuf;                         // [TOKENS, 768] aliases cbuf..vbuf

    // 1. gating: x_res -> out, x_in -> xin, LN1 -> hbuf, h_post -> hpost
    gating_kernel<<<TOKENS, 64, 0, stream>>>(
        x, norm_w, phi_pre, phi_post, phi_res, b_pre, b_post, b_res,
        alpha_pre, alpha_post, alpha_res, ln1_w, ln1_b,
        out, xin, hbuf, hpost);

    // 2. QKV projections
    {
        dim3 grid(DIM / 64, TOKENS / 64), block(16, 16);
        gemm_kernel<0><<<grid, block, 0, stream>>>(hbuf, Wq, nullptr, qbuf, TOKENS, DIM, DIM);
        gemm_kernel<0><<<grid, block, 0, stream>>>(hbuf, Wk, nullptr, kbuf, TOKENS, DIM, DIM);
        gemm_kernel<0><<<grid, block, 0, stream>>>(hbuf, Wv, nullptr, vbuf, TOKENS, DIM, DIM);
    }

    // 3. attention -> cbuf
    {
        dim3 grid(SEQ, BATCH * NH);
        attn_kernel<<<grid, 256, 0, stream>>>(qbuf, kbuf, vbuf, cbuf);
    }

    // 4. x1 = x_in + attn_out @ Wo  -> hbuf
    {
        dim3 grid(DIM / 64, TOKENS / 64), block(16, 16);
        gemm_kernel<1><<<grid, block, 0, stream>>>(cbuf, Wo, xin, hbuf, TOKENS, DIM, DIM);
    }

    // 5. h2 = LN2(x1) -> xin
    ln_kernel<<<TOKENS, 64, 0, stream>>>(hbuf, ln2_w, ln2_b, xin);

    // 6. g = gelu(h2 @ W1) -> gbuf
    {
        dim3 grid(MLP / 64, TOKENS / 64), block(16, 16);
        gemm_kernel<2><<<grid, block, 0, stream>>>(xin, W1, nullptr, gbuf, TOKENS, MLP, DIM);
    }

    // 7. y = x1 + g @ W2 -> xin
    {
        dim3 grid(DIM / 64, TOKENS / 64), block(16, 16);
        gemm_kernel<1><<<grid, block, 0, stream>>>(gbuf, W2, hbuf, xin, TOKENS, DIM, MLP);
    }

    // 8. out += y * h_post
    {
        const int n4 = TOKENS * (ND / 4);
        final_kernel<<<(n4 + 255) / 256, 256, 0, stream>>>(xin, hpost, out);
    }
}

// Round 2
// 1385.228 us; speedup vs baseline: 6.4973x; 6.4973x over previous
//
#include <hip/hip_runtime.h>
#include <hip/hip_bf16.h>
#include <math.h>

// Problem constants
#define BATCH 32
#define SEQ   1024
#define NS    4        // n streams
#define DIM   192      // d per stream
#define ND    768      // n*d
#define NH    3        // attention heads
#define HD    64       // head dim
#define MLP   768
#define TOKENS (BATCH*SEQ)   // 32768

__device__ inline float gelu_tanh(float x) {
    float x3 = x * x * x;
    return 0.5f * x * (1.0f + tanhf(0.7978845608028654f * (x + 0.044715f * x3)));
}

// ---------------------------------------------------------------------------
// Kernel 1: per-token gating. One wave (64 threads) per token.
// ---------------------------------------------------------------------------
__global__ __launch_bounds__(64) void gating_kernel(
    const float* __restrict__ x, const float* __restrict__ norm_w,
    const float* __restrict__ phi_pre, const float* __restrict__ phi_post,
    const float* __restrict__ phi_res, const float* __restrict__ b_pre,
    const float* __restrict__ b_post, const float* __restrict__ b_res,
    const float* __restrict__ alpha_pre, const float* __restrict__ alpha_post,
    const float* __restrict__ alpha_res,
    const float* __restrict__ ln1_w, const float* __restrict__ ln1_b,
    float* __restrict__ out, float* __restrict__ xin,
    float* __restrict__ hbuf, float* __restrict__ hpost)
{
    const int token = blockIdx.x;
    const int lane  = threadIdx.x;
    const float* xt = x + (size_t)token * ND;

    __shared__ float ldsx[ND];

    float4 xv[3];
#pragma unroll
    for (int r = 0; r < 3; r++) {
        xv[r] = ((const float4*)xt)[lane + 64 * r];
        ((float4*)ldsx)[lane + 64 * r] = xv[r];
    }

    float ssq = 0.f;
#pragma unroll
    for (int r = 0; r < 3; r++)
        ssq += xv[r].x*xv[r].x + xv[r].y*xv[r].y + xv[r].z*xv[r].z + xv[r].w*xv[r].w;
#pragma unroll
    for (int off = 32; off; off >>= 1) ssq += __shfl_xor(ssq, off);
    const float rinv = rsqrtf(ssq / (float)ND + 1e-8f);  // 1/rms

    float acc[24];
#pragma unroll
    for (int p = 0; p < 24; p++) acc[p] = 0.f;

#pragma unroll
    for (int r = 0; r < 3; r++) {
        const int g = lane + 64 * r;
        const float4 wv = ((const float4*)norm_w)[g];
        float s[4];
        s[0] = xv[r].x * wv.x * rinv;
        s[1] = xv[r].y * wv.y * rinv;
        s[2] = xv[r].z * wv.z * rinv;
        s[3] = xv[r].w * wv.w * rinv;
#pragma unroll
        for (int e = 0; e < 4; e++) {
            const int j = 4 * g + e;
            const float sj = s[e];
            const float* pp = phi_pre + (size_t)j * 4;
#pragma unroll
            for (int p = 0; p < 4; p++) acc[p] += sj * pp[p];
            const float* po = phi_post + (size_t)j * 4;
#pragma unroll
            for (int p = 0; p < 4; p++) acc[4 + p] += sj * po[p];
            const float* pr = phi_res + (size_t)j * 16;
#pragma unroll
            for (int p = 0; p < 16; p++) acc[8 + p] += sj * pr[p];
        }
    }
#pragma unroll
    for (int p = 0; p < 24; p++) {
#pragma unroll
        for (int off = 32; off; off >>= 1) acc[p] += __shfl_xor(acc[p], off);
    }

    const float apre = alpha_pre[0], apost = alpha_post[0], ares = alpha_res[0];
    float hpre[NS], hpo[NS], hres[NS * NS];
#pragma unroll
    for (int i = 0; i < NS; i++) {
        hpre[i] = 1.0f / (1.0f + expf(-(apre * acc[i] + b_pre[i])));
        hpo[i]  = 2.0f / (1.0f + expf(-(apost * acc[4 + i] + b_post[i])));
    }
#pragma unroll
    for (int p = 0; p < NS * NS; p++) hres[p] = ares * acc[8 + p] + b_res[p];

    float gmax = hres[0];
#pragma unroll
    for (int p = 1; p < 16; p++) gmax = fmaxf(gmax, hres[p]);
#pragma unroll
    for (int p = 0; p < 16; p++) hres[p] = expf(hres[p] - gmax);
    for (int it = 0; it < 20; it++) {
#pragma unroll
        for (int i = 0; i < NS; i++) {
            float rs = hres[i*4+0] + hres[i*4+1] + hres[i*4+2] + hres[i*4+3];
            float inv = 1.0f / (rs + 1e-8f);
#pragma unroll
            for (int j = 0; j < NS; j++) hres[i*4+j] *= inv;
        }
#pragma unroll
        for (int j = 0; j < NS; j++) {
            float cs = hres[0*4+j] + hres[1*4+j] + hres[2*4+j] + hres[3*4+j];
            float inv = 1.0f / (cs + 1e-8f);
#pragma unroll
            for (int i = 0; i < NS; i++) hres[i*4+j] *= inv;
        }
    }

    __syncthreads();

    float* ot = out + (size_t)token * ND;
#pragma unroll
    for (int r = 0; r < 3; r++) {
        const int g  = lane + 64 * r;
        const int p0 = 4 * g;
        const int i  = p0 / DIM;
        const int d0 = p0 % DIM;
        float4 o;
        o.x = hres[i*4+0]*ldsx[0*DIM+d0+0] + hres[i*4+1]*ldsx[1*DIM+d0+0]
            + hres[i*4+2]*ldsx[2*DIM+d0+0] + hres[i*4+3]*ldsx[3*DIM+d0+0];
        o.y = hres[i*4+0]*ldsx[0*DIM+d0+1] + hres[i*4+1]*ldsx[1*DIM+d0+1]
            + hres[i*4+2]*ldsx[2*DIM+d0+1] + hres[i*4+3]*ldsx[3*DIM+d0+1];
        o.z = hres[i*4+0]*ldsx[0*DIM+d0+2] + hres[i*4+1]*ldsx[1*DIM+d0+2]
            + hres[i*4+2]*ldsx[2*DIM+d0+2] + hres[i*4+3]*ldsx[3*DIM+d0+2];
        o.w = hres[i*4+0]*ldsx[0*DIM+d0+3] + hres[i*4+1]*ldsx[1*DIM+d0+3]
            + hres[i*4+2]*ldsx[2*DIM+d0+3] + hres[i*4+3]*ldsx[3*DIM+d0+3];
        ((float4*)ot)[g] = o;
    }

    float xi[3];
#pragma unroll
    for (int r = 0; r < 3; r++) {
        const int d = lane + 64 * r;
        xi[r] = hpre[0]*ldsx[d] + hpre[1]*ldsx[DIM+d]
              + hpre[2]*ldsx[2*DIM+d] + hpre[3]*ldsx[3*DIM+d];
    }
    float sum = xi[0] + xi[1] + xi[2];
#pragma unroll
    for (int off = 32; off; off >>= 1) sum += __shfl_xor(sum, off);
    const float mean = sum / (float)DIM;
    float vs = (xi[0]-mean)*(xi[0]-mean) + (xi[1]-mean)*(xi[1]-mean) + (xi[2]-mean)*(xi[2]-mean);
#pragma unroll
    for (int off = 32; off; off >>= 1) vs += __shfl_xor(vs, off);
    const float inv = rsqrtf(vs / (float)DIM + 1e-5f);

    float* xint = xin  + (size_t)token * DIM;
    float* ht   = hbuf + (size_t)token * DIM;
#pragma unroll
    for (int r = 0; r < 3; r++) {
        const int d = lane + 64 * r;
        xint[d] = xi[r];
        ht[d]   = (xi[r] - mean) * inv * ln1_w[d] + ln1_b[d];
    }
    if (lane < NS) hpost[(size_t)token * NS + lane] = hpo[lane];
}

// ---------------------------------------------------------------------------
// Tiled fp32 GEMM: C[M,N] = op(A[M,K] @ B[K,N] [+ R]).  OP: 0 plain, 1 +R, 2 gelu
// ---------------------------------------------------------------------------
template<int OP>
__global__ __launch_bounds__(256) void gemm_kernel(
    const float* __restrict__ A, const float* __restrict__ Bm,
    const float* __restrict__ R, float* __restrict__ C,
    int M, int N, int K)
{
    __shared__ float As[16][64 + 4];
    __shared__ float Bs[16][64 + 4];
    const int tx = threadIdx.x;
    const int ty = threadIdx.y;
    const int l  = ty * 16 + tx;
    const int m0 = blockIdx.y * 64;
    const int n0 = blockIdx.x * 64;

    float c[4][4];
#pragma unroll
    for (int i = 0; i < 4; i++)
#pragma unroll
        for (int j = 0; j < 4; j++) c[i][j] = 0.f;

    for (int k0 = 0; k0 < K; k0 += 16) {
        {
            const int row = l >> 2, kq = (l & 3) * 4;
            const float4 a = *(const float4*)(A + (size_t)(m0 + row) * K + k0 + kq);
            As[kq+0][row] = a.x; As[kq+1][row] = a.y;
            As[kq+2][row] = a.z; As[kq+3][row] = a.w;
        }
        {
            const int kr = l >> 4, nq = (l & 15) * 4;
            const float4 b = *(const float4*)(Bm + (size_t)(k0 + kr) * N + n0 + nq);
            Bs[kr][nq+0] = b.x; Bs[kr][nq+1] = b.y;
            Bs[kr][nq+2] = b.z; Bs[kr][nq+3] = b.w;
        }
        __syncthreads();
#pragma unroll
        for (int kk = 0; kk < 16; kk++) {
            float a[4], b[4];
#pragma unroll
            for (int i = 0; i < 4; i++) a[i] = As[kk][ty * 4 + i];
#pragma unroll
            for (int j = 0; j < 4; j++) b[j] = Bs[kk][tx * 4 + j];
#pragma unroll
            for (int i = 0; i < 4; i++)
#pragma unroll
                for (int j = 0; j < 4; j++) c[i][j] += a[i] * b[j];
        }
        __syncthreads();
    }

#pragma unroll
    for (int i = 0; i < 4; i++) {
        const int row = m0 + ty * 4 + i;
        const size_t base = (size_t)row * N + n0 + tx * 4;
#pragma unroll
        for (int j = 0; j < 4; j++) {
            float v = c[i][j];
            if (OP == 1) v += R[base + j];
            if (OP == 2) v = gelu_tanh(v);
            C[base + j] = v;
        }
    }
}

// ---------------------------------------------------------------------------
// Flash attention fp32: one block per (q-tile of 64, b*h). 256 threads (16x16),
// 4x4 microtile. Q/K staged transposed [d][m] in LDS so the S inner loop reads
// both operands as float4; P round-trips through LDS as [k][q]; V as [k][d].
// Online softmax; row stats via __shfl_xor within 16-lane tx-groups.
// ---------------------------------------------------------------------------
#define QT 64         // q-tile
#define KT 64         // k-tile
#define LP 68         // padded leading stride (68*4B: rows 17 banks apart)

__global__ __launch_bounds__(256) void attn_kernel(
    const float* __restrict__ Q, const float* __restrict__ Kb,
    const float* __restrict__ V, float* __restrict__ O)
{
    const int qt = blockIdx.x;       // 0..15
    const int bh = blockIdx.y;       // 0..95
    const int b  = bh / NH, h = bh % NH;
    const int tid = threadIdx.x;
    const int tx = tid & 15;         // k-col group / out-dim group
    const int ty = tid >> 4;         // q-row group

    __shared__ float Qs[HD][LP];     // [d][q]  (transposed)
    __shared__ float Ks[HD][LP];     // [d][k]  (transposed)
    __shared__ float Vs[KT][LP];     // [k][d]
    __shared__ float Ps[KT][LP];     // [k][q]  (transposed)

    const int q0 = qt * QT;
    const size_t qkv_base = (size_t)b * SEQ;

    // stage Q tile transposed: thread t: row r = t/4, d0 = (t%4)*16
    {
        const int r = tid >> 2, d0 = (tid & 3) * 16;
        const float* src = Q + (qkv_base + q0 + r) * DIM + h * HD + d0;
#pragma unroll
        for (int q4 = 0; q4 < 4; q4++) {
            const float4 v = ((const float4*)src)[q4];
            Qs[d0 + q4*4 + 0][r] = v.x;
            Qs[d0 + q4*4 + 1][r] = v.y;
            Qs[d0 + q4*4 + 2][r] = v.z;
            Qs[d0 + q4*4 + 3][r] = v.w;
        }
    }

    float o[4][4];
    float m[4], lsum[4];
#pragma unroll
    for (int i = 0; i < 4; i++) {
        m[i] = -1e30f; lsum[i] = 0.f;
#pragma unroll
        for (int j = 0; j < 4; j++) o[i][j] = 0.f;
    }

    for (int kt = 0; kt < SEQ / KT; kt++) {
        __syncthreads();   // prior PV reads of Vs/Ps done; Qs staged (first iter)
        // stage K (transposed) and V tiles
        {
            const int r = tid >> 2, d0 = (tid & 3) * 16;
            const float* ksrc = Kb + (qkv_base + kt * KT + r) * DIM + h * HD + d0;
            const float* vsrc = V  + (qkv_base + kt * KT + r) * DIM + h * HD + d0;
#pragma unroll
            for (int q4 = 0; q4 < 4; q4++) {
                const float4 kv = ((const float4*)ksrc)[q4];
                Ks[d0 + q4*4 + 0][r] = kv.x;
                Ks[d0 + q4*4 + 1][r] = kv.y;
                Ks[d0 + q4*4 + 2][r] = kv.z;
                Ks[d0 + q4*4 + 3][r] = kv.w;
                ((float4*)&Vs[r][d0])[q4] = ((const float4*)vsrc)[q4];
            }
        }
        __syncthreads();

        // S tile: c[i][j] = sum_d Qs[d][ty*4+i] * Ks[d][tx*4+j]
        float c[4][4];
#pragma unroll
        for (int i = 0; i < 4; i++)
#pragma unroll
            for (int j = 0; j < 4; j++) c[i][j] = 0.f;
        for (int d = 0; d < HD; d++) {
            const float4 a = *(const float4*)&Qs[d][ty * 4];
            const float4 bb = *(const float4*)&Ks[d][tx * 4];
            const float av[4] = {a.x, a.y, a.z, a.w};
            const float bv[4] = {bb.x, bb.y, bb.z, bb.w};
#pragma unroll
            for (int i = 0; i < 4; i++)
#pragma unroll
                for (int j = 0; j < 4; j++) c[i][j] += av[i] * bv[j];
        }

        // online softmax (scale 1/8); row reductions within 16-lane tx-groups
        float alpha[4];
#pragma unroll
        for (int i = 0; i < 4; i++) {
            float tmax = fmaxf(fmaxf(c[i][0], c[i][1]), fmaxf(c[i][2], c[i][3]));
#pragma unroll
            for (int off = 1; off < 16; off <<= 1)
                tmax = fmaxf(tmax, __shfl_xor(tmax, off));
            tmax *= 0.125f;
            const float mnew = fmaxf(m[i], tmax);
            alpha[i] = __expf(m[i] - mnew);
            m[i] = mnew;
            float rs = 0.f;
#pragma unroll
            for (int j = 0; j < 4; j++) {
                c[i][j] = __expf(c[i][j] * 0.125f - mnew);
                rs += c[i][j];
            }
#pragma unroll
            for (int off = 1; off < 16; off <<= 1)
                rs += __shfl_xor(rs, off);
            lsum[i] = lsum[i] * alpha[i] + rs;
#pragma unroll
            for (int j = 0; j < 4; j++) o[i][j] *= alpha[i];
        }

        // write P transposed: Ps[k][q]
#pragma unroll
        for (int j = 0; j < 4; j++)
#pragma unroll
            for (int i = 0; i < 4; i++)
                Ps[tx * 4 + j][ty * 4 + i] = c[i][j];
        __syncthreads();

        // O += P^T-read @ V: o[i][j] += sum_k Ps[k][ty*4+i] * Vs[k][tx*4+j]
        for (int k = 0; k < KT; k++) {
            const float4 p = *(const float4*)&Ps[k][ty * 4];
            const float4 vv = *(const float4*)&Vs[k][tx * 4];
            const float pv[4] = {p.x, p.y, p.z, p.w};
            const float vvv[4] = {vv.x, vv.y, vv.z, vv.w};
#pragma unroll
            for (int i = 0; i < 4; i++)
#pragma unroll
                for (int j = 0; j < 4; j++) o[i][j] += pv[i] * vvv[j];
        }
    }

    // epilogue: divide by l, store
#pragma unroll
    for (int i = 0; i < 4; i++) {
        const float inv = 1.0f / lsum[i];
        const size_t row = qkv_base + q0 + ty * 4 + i;
        float4 ov;
        ov.x = o[i][0] * inv; ov.y = o[i][1] * inv;
        ov.z = o[i][2] * inv; ov.w = o[i][3] * inv;
        *(float4*)(O + row * DIM + h * HD + tx * 4) = ov;
    }
}

// ---------------------------------------------------------------------------
// LayerNorm over 192, one wave per token
// ---------------------------------------------------------------------------
__global__ __launch_bounds__(64) void ln_kernel(
    const float* __restrict__ X, const float* __restrict__ w,
    const float* __restrict__ bb, float* __restrict__ Y)
{
    const int token = blockIdx.x;
    const int lane  = threadIdx.x;
    const float* xt = X + (size_t)token * DIM;
    float v[3];
#pragma unroll
    for (int r = 0; r < 3; r++) v[r] = xt[lane + 64 * r];
    float sum = v[0] + v[1] + v[2];
#pragma unroll
    for (int off = 32; off; off >>= 1) sum += __shfl_xor(sum, off);
    const float mean = sum / (float)DIM;
    float vs = (v[0]-mean)*(v[0]-mean) + (v[1]-mean)*(v[1]-mean) + (v[2]-mean)*(v[2]-mean);
#pragma unroll
    for (int off = 32; off; off >>= 1) vs += __shfl_xor(vs, off);
    const float inv = rsqrtf(vs / (float)DIM + 1e-5f);
    float* yt = Y + (size_t)token * DIM;
#pragma unroll
    for (int r = 0; r < 3; r++) {
        const int d = lane + 64 * r;
        yt[d] = (v[r] - mean) * inv * w[d] + bb[d];
    }
}

// ---------------------------------------------------------------------------
// Final: out[token, i, d] += y[token, d] * hpost[token, i]
// ---------------------------------------------------------------------------
__global__ __launch_bounds__(256) void final_kernel(
    const float* __restrict__ y, const float* __restrict__ hpost,
    float* __restrict__ out)
{
    const size_t g = (size_t)blockIdx.x * blockDim.x + threadIdx.x;
    if (g >= (size_t)TOKENS * (ND / 4)) return;
    const int token = (int)(g / (ND / 4));
    const int f     = (int)(g % (ND / 4));
    const int i     = f / (DIM / 4);
    const int d4    = f % (DIM / 4);
    const float4 yv = ((const float4*)(y + (size_t)token * DIM))[d4];
    const float hp  = hpost[(size_t)token * NS + i];
    float4* op = (float4*)out + g;
    float4 ov = *op;
    ov.x += yv.x * hp; ov.y += yv.y * hp; ov.z += yv.z * hp; ov.w += yv.w * hp;
    *op = ov;
}

// ---------------------------------------------------------------------------
extern "C" void kernel_launch(void* const* d_in, const int* in_sizes, int n_in,
                              void* d_out, int out_size, void* d_ws, size_t ws_size,
                              hipStream_t stream) {
    const float* x         = (const float*)d_in[0];
    const float* norm_w    = (const float*)d_in[1];
    const float* phi_pre   = (const float*)d_in[2];
    const float* phi_post  = (const float*)d_in[3];
    const float* phi_res   = (const float*)d_in[4];
    const float* b_pre     = (const float*)d_in[5];
    const float* b_post    = (const float*)d_in[6];
    const float* b_res     = (const float*)d_in[7];
    const float* alpha_pre = (const float*)d_in[8];
    const float* alpha_post= (const float*)d_in[9];
    const float* alpha_res = (const float*)d_in[10];
    const float* ln1_w     = (const float*)d_in[11];
    const float* ln1_b     = (const float*)d_in[12];
    const float* Wq        = (const float*)d_in[13];
    const float* Wk        = (const float*)d_in[14];
    const float* Wv        = (const float*)d_in[15];
    const float* Wo        = (const float*)d_in[16];
    const float* ln2_w     = (const float*)d_in[17];
    const float* ln2_b     = (const float*)d_in[18];
    const float* W1        = (const float*)d_in[19];
    const float* W2        = (const float*)d_in[20];

    float* out = (float*)d_out;
    float* ws  = (float*)d_ws;

    const size_t TB = (size_t)TOKENS * DIM;
    float* xin   = ws;
    float* hbuf  = ws + TB;
    float* cbuf  = ws + 2 * TB;
    float* qbuf  = ws + 3 * TB;
    float* kbuf  = ws + 4 * TB;
    float* vbuf  = ws + 5 * TB;
    float* hpost = ws + 6 * TB;
    float* gbuf  = cbuf;                         // [TOKENS, 768] aliases cbuf..vbuf

    // 1. gating: x_res -> out, x_in -> xin, LN1 -> hbuf, h_post -> hpost
    gating_kernel<<<TOKENS, 64, 0, stream>>>(
        x, norm_w, phi_pre, phi_post, phi_res, b_pre, b_post, b_res,
        alpha_pre, alpha_post, alpha_res, ln1_w, ln1_b,
        out, xin, hbuf, hpost);

    // 2. QKV projections
    {
        dim3 grid(DIM / 64, TOKENS / 64), block(16, 16);
        gemm_kernel<0><<<grid, block, 0, stream>>>(hbuf, Wq, nullptr, qbuf, TOKENS, DIM, DIM);
        gemm_kernel<0><<<grid, block, 0, stream>>>(hbuf, Wk, nullptr, kbuf, TOKENS, DIM, DIM);
        gemm_kernel<0><<<grid, block, 0, stream>>>(hbuf, Wv, nullptr, vbuf, TOKENS, DIM, DIM);
    }

    // 3. attention -> cbuf
    {
        dim3 grid(SEQ / QT, BATCH * NH);
        attn_kernel<<<grid, 256, 0, stream>>>(qbuf, kbuf, vbuf, cbuf);
    }

    // 4. x1 = x_in + attn_out @ Wo  -> hbuf
    {
        dim3 grid(DIM / 64, TOKENS / 64), block(16, 16);
        gemm_kernel<1><<<grid, block, 0, stream>>>(cbuf, Wo, xin, hbuf, TOKENS, DIM, DIM);
    }

    // 5. h2 = LN2(x1) -> xin
    ln_kernel<<<TOKENS, 64, 0, stream>>>(hbuf, ln2_w, ln2_b, xin);

    // 6. g = gelu(h2 @ W1) -> gbuf
    {
        dim3 grid(MLP / 64, TOKENS / 64), block(16, 16);
        gemm_kernel<2><<<grid, block, 0, stream>>>(xin, W1, nullptr, gbuf, TOKENS, MLP, DIM);
    }

    // 7. y = x1 + g @ W2 -> xin
    {
        dim3 grid(DIM / 64, TOKENS / 64), block(16, 16);
        gemm_kernel<1><<<grid, block, 0, stream>>>(gbuf, W2, hbuf, xin, TOKENS, DIM, MLP);
    }

    // 8. out += y * h_post
    {
        const int n4 = TOKENS * (ND / 4);
        final_kernel<<<(n4 + 255) / 256, 256, 0, stream>>>(xin, hpost, out);
    }
}

// Round 3
// 893.358 us; speedup vs baseline: 10.0745x; 1.5506x over previous
//
#include <hip/hip_runtime.h>
#include <hip/hip_bf16.h>
#include <math.h>

// Problem constants
#define BATCH 32
#define SEQ   1024
#define NS    4
#define DIM   192
#define ND    768
#define NH    3
#define HD    64
#define MLP   768
#define TOKENS (BATCH*SEQ)   // 32768

typedef __bf16 bf16;
typedef bf16  bf16x8 __attribute__((ext_vector_type(8)));
typedef float f32x4  __attribute__((ext_vector_type(4)));

#define MFMA16(a,b,c) __builtin_amdgcn_mfma_f32_16x16x32_bf16(a,b,c,0,0,0)

__device__ inline float gelu_tanh(float x) {
    float x3 = x * x * x;
    return 0.5f * x * (1.0f + tanhf(0.7978845608028654f * (x + 0.044715f * x3)));
}

// ---------------------------------------------------------------------------
// Weight convert + transpose: dst[N][K] (bf16) = src[K][N] (fp32)
// ---------------------------------------------------------------------------
__global__ __launch_bounds__(256) void wconv_kernel(
    const float* __restrict__ src, bf16* __restrict__ dst, int K, int N)
{
    __shared__ float t[32][33];
    const int x = threadIdx.x, y = threadIdx.y;     // 32 x 8
    const int k0 = blockIdx.y * 32, n0 = blockIdx.x * 32;
#pragma unroll
    for (int i = 0; i < 4; i++)
        t[y + 8*i][x] = src[(size_t)(k0 + y + 8*i) * N + n0 + x];
    __syncthreads();
#pragma unroll
    for (int i = 0; i < 4; i++)
        dst[(size_t)(n0 + y + 8*i) * K + k0 + x] = (bf16)t[x][y + 8*i];
}

// ---------------------------------------------------------------------------
// Gating: one wave per token. x_res -> out, x_in(fp32) -> xin,
// LN1(x_in)(bf16) -> h1, h_post -> hpost
// ---------------------------------------------------------------------------
__global__ __launch_bounds__(64) void gating_kernel(
    const float* __restrict__ x, const float* __restrict__ norm_w,
    const float* __restrict__ phi_pre, const float* __restrict__ phi_post,
    const float* __restrict__ phi_res, const float* __restrict__ b_pre,
    const float* __restrict__ b_post, const float* __restrict__ b_res,
    const float* __restrict__ alpha_pre, const float* __restrict__ alpha_post,
    const float* __restrict__ alpha_res,
    const float* __restrict__ ln1_w, const float* __restrict__ ln1_b,
    float* __restrict__ out, float* __restrict__ xin,
    bf16* __restrict__ h1, float* __restrict__ hpost)
{
    const int token = blockIdx.x;
    const int lane  = threadIdx.x;
    const float* xt = x + (size_t)token * ND;

    __shared__ float ldsx[ND];

    float4 xv[3];
#pragma unroll
    for (int r = 0; r < 3; r++) {
        xv[r] = ((const float4*)xt)[lane + 64 * r];
        ((float4*)ldsx)[lane + 64 * r] = xv[r];
    }

    float ssq = 0.f;
#pragma unroll
    for (int r = 0; r < 3; r++)
        ssq += xv[r].x*xv[r].x + xv[r].y*xv[r].y + xv[r].z*xv[r].z + xv[r].w*xv[r].w;
#pragma unroll
    for (int off = 32; off; off >>= 1) ssq += __shfl_xor(ssq, off);
    const float rinv = rsqrtf(ssq / (float)ND + 1e-8f);

    float acc[24];
#pragma unroll
    for (int p = 0; p < 24; p++) acc[p] = 0.f;

#pragma unroll
    for (int r = 0; r < 3; r++) {
        const int g = lane + 64 * r;
        const float4 wv = ((const float4*)norm_w)[g];
        float s[4];
        s[0] = xv[r].x * wv.x * rinv;
        s[1] = xv[r].y * wv.y * rinv;
        s[2] = xv[r].z * wv.z * rinv;
        s[3] = xv[r].w * wv.w * rinv;
#pragma unroll
        for (int e = 0; e < 4; e++) {
            const int j = 4 * g + e;
            const float sj = s[e];
            const float* pp = phi_pre + (size_t)j * 4;
#pragma unroll
            for (int p = 0; p < 4; p++) acc[p] += sj * pp[p];
            const float* po = phi_post + (size_t)j * 4;
#pragma unroll
            for (int p = 0; p < 4; p++) acc[4 + p] += sj * po[p];
            const float* pr = phi_res + (size_t)j * 16;
#pragma unroll
            for (int p = 0; p < 16; p++) acc[8 + p] += sj * pr[p];
        }
    }
#pragma unroll
    for (int p = 0; p < 24; p++) {
#pragma unroll
        for (int off = 32; off; off >>= 1) acc[p] += __shfl_xor(acc[p], off);
    }

    const float apre = alpha_pre[0], apost = alpha_post[0], ares = alpha_res[0];
    float hpre[NS], hpo[NS], hres[NS * NS];
#pragma unroll
    for (int i = 0; i < NS; i++) {
        hpre[i] = 1.0f / (1.0f + expf(-(apre * acc[i] + b_pre[i])));
        hpo[i]  = 2.0f / (1.0f + expf(-(apost * acc[4 + i] + b_post[i])));
    }
#pragma unroll
    for (int p = 0; p < NS * NS; p++) hres[p] = ares * acc[8 + p] + b_res[p];

    float gmax = hres[0];
#pragma unroll
    for (int p = 1; p < 16; p++) gmax = fmaxf(gmax, hres[p]);
#pragma unroll
    for (int p = 0; p < 16; p++) hres[p] = expf(hres[p] - gmax);
    for (int it = 0; it < 20; it++) {
#pragma unroll
        for (int i = 0; i < NS; i++) {
            float rs = hres[i*4+0] + hres[i*4+1] + hres[i*4+2] + hres[i*4+3];
            float inv = 1.0f / (rs + 1e-8f);
#pragma unroll
            for (int j = 0; j < NS; j++) hres[i*4+j] *= inv;
        }
#pragma unroll
        for (int j = 0; j < NS; j++) {
            float cs = hres[0*4+j] + hres[1*4+j] + hres[2*4+j] + hres[3*4+j];
            float inv = 1.0f / (cs + 1e-8f);
#pragma unroll
            for (int i = 0; i < NS; i++) hres[i*4+j] *= inv;
        }
    }

    __syncthreads();

    float* ot = out + (size_t)token * ND;
#pragma unroll
    for (int r = 0; r < 3; r++) {
        const int g  = lane + 64 * r;
        const int p0 = 4 * g;
        const int i  = p0 / DIM;
        const int d0 = p0 % DIM;
        float4 o;
        o.x = hres[i*4+0]*ldsx[0*DIM+d0+0] + hres[i*4+1]*ldsx[1*DIM+d0+0]
            + hres[i*4+2]*ldsx[2*DIM+d0+0] + hres[i*4+3]*ldsx[3*DIM+d0+0];
        o.y = hres[i*4+0]*ldsx[0*DIM+d0+1] + hres[i*4+1]*ldsx[1*DIM+d0+1]
            + hres[i*4+2]*ldsx[2*DIM+d0+1] + hres[i*4+3]*ldsx[3*DIM+d0+1];
        o.z = hres[i*4+0]*ldsx[0*DIM+d0+2] + hres[i*4+1]*ldsx[1*DIM+d0+2]
            + hres[i*4+2]*ldsx[2*DIM+d0+2] + hres[i*4+3]*ldsx[3*DIM+d0+2];
        o.w = hres[i*4+0]*ldsx[0*DIM+d0+3] + hres[i*4+1]*ldsx[1*DIM+d0+3]
            + hres[i*4+2]*ldsx[2*DIM+d0+3] + hres[i*4+3]*ldsx[3*DIM+d0+3];
        ((float4*)ot)[g] = o;
    }

    float xi[3];
#pragma unroll
    for (int r = 0; r < 3; r++) {
        const int d = lane + 64 * r;
        xi[r] = hpre[0]*ldsx[d] + hpre[1]*ldsx[DIM+d]
              + hpre[2]*ldsx[2*DIM+d] + hpre[3]*ldsx[3*DIM+d];
    }
    float sum = xi[0] + xi[1] + xi[2];
#pragma unroll
    for (int off = 32; off; off >>= 1) sum += __shfl_xor(sum, off);
    const float mean = sum / (float)DIM;
    float vs = (xi[0]-mean)*(xi[0]-mean) + (xi[1]-mean)*(xi[1]-mean) + (xi[2]-mean)*(xi[2]-mean);
#pragma unroll
    for (int off = 32; off; off >>= 1) vs += __shfl_xor(vs, off);
    const float inv = rsqrtf(vs / (float)DIM + 1e-5f);

    float* xint = xin + (size_t)token * DIM;
    bf16*  ht   = h1  + (size_t)token * DIM;
#pragma unroll
    for (int r = 0; r < 3; r++) {
        const int d = lane + 64 * r;
        xint[d] = xi[r];
        ht[d]   = (bf16)((xi[r] - mean) * inv * ln1_w[d] + ln1_b[d]);
    }
    if (lane < NS) hpost[(size_t)token * NS + lane] = hpo[lane];
}

// ---------------------------------------------------------------------------
// bf16 MFMA GEMM: C[M,N] = epi(A[M,K] @ Bt[N,K]^T [+R])
// 128x64 tile, BK=64, 256 threads (4 waves), wave = 64x32 region.
// XOR-swizzled LDS (conflict-free ds_read_b128). Register staging.
// EPI: 0 = bf16 out, 1 = +R fp32 out, 2 = gelu bf16 out
// ---------------------------------------------------------------------------
template<int EPI>
__global__ __launch_bounds__(256) void mfma_gemm(
    const bf16* __restrict__ A, const bf16* __restrict__ Bt,
    const float* __restrict__ R, float* __restrict__ Cf, bf16* __restrict__ Cb,
    int M, int N, int K)
{
    __shared__ bf16 As[128 * 64];
    __shared__ bf16 Bs[64 * 64];
    const int tid  = threadIdx.x;
    const int lane = tid & 63, w = tid >> 6;
    const int quad = lane >> 4, c = lane & 15;
    const int m0 = blockIdx.y * 128, n0 = blockIdx.x * 64;
    const int wm = (w >> 1) * 64, wn = (w & 1) * 32;

    // staging: A = 16 batches of 64 slots (wave w: batches 4w..4w+3)
    //          B = 8 batches (wave w: batches 2w..2w+1)
    int sa[4], sb[2];
    size_t aoff[4], boff[2];
#pragma unroll
    for (int j = 0; j < 4; j++) {
        sa[j] = (w * 4 + j) * 64 + lane;
        const int m = sa[j] >> 3, gp = sa[j] & 7;
        const int g = gp ^ (m & 7);
        aoff[j] = (size_t)(m0 + m) * K + g * 8;
    }
#pragma unroll
    for (int j = 0; j < 2; j++) {
        sb[j] = (w * 2 + j) * 64 + lane;
        const int n = sb[j] >> 3, gp = sb[j] & 7;
        const int g = gp ^ (n & 7);
        boff[j] = (size_t)(n0 + n) * K + g * 8;
    }

    f32x4 acc[4][2];
#pragma unroll
    for (int i = 0; i < 4; i++)
#pragma unroll
        for (int j = 0; j < 2; j++) acc[i][j] = (f32x4){0.f, 0.f, 0.f, 0.f};

    for (int k0 = 0; k0 < K; k0 += 64) {
        uint4 av[4], bv[2];
#pragma unroll
        for (int j = 0; j < 4; j++) av[j] = *(const uint4*)(A + aoff[j] + k0);
#pragma unroll
        for (int j = 0; j < 2; j++) bv[j] = *(const uint4*)(Bt + boff[j] + k0);
        __syncthreads();
#pragma unroll
        for (int j = 0; j < 4; j++) *(uint4*)(As + sa[j] * 8) = av[j];
#pragma unroll
        for (int j = 0; j < 2; j++) *(uint4*)(Bs + sb[j] * 8) = bv[j];
        __syncthreads();
#pragma unroll
        for (int ch = 0; ch < 2; ch++) {
            bf16x8 af[4], bfr[2];
#pragma unroll
            for (int mt = 0; mt < 4; mt++)
                af[mt] = *(const bf16x8*)(As + (wm + mt*16 + c) * 64
                                             + (((ch*4 + quad) ^ (c & 7)) * 8));
#pragma unroll
            for (int nt = 0; nt < 2; nt++)
                bfr[nt] = *(const bf16x8*)(Bs + (wn + nt*16 + c) * 64
                                              + (((ch*4 + quad) ^ (c & 7)) * 8));
#pragma unroll
            for (int mt = 0; mt < 4; mt++)
#pragma unroll
                for (int nt = 0; nt < 2; nt++)
                    acc[mt][nt] = MFMA16(af[mt], bfr[nt], acc[mt][nt]);
        }
    }

#pragma unroll
    for (int mt = 0; mt < 4; mt++)
#pragma unroll
        for (int nt = 0; nt < 2; nt++)
#pragma unroll
            for (int r = 0; r < 4; r++) {
                const int row = m0 + wm + mt*16 + quad*4 + r;
                const int col = n0 + wn + nt*16 + c;
                const size_t idx = (size_t)row * N + col;
                float v = acc[mt][nt][r];
                if (EPI == 1)      Cf[idx] = v + R[idx];
                else if (EPI == 2) Cb[idx] = (bf16)gelu_tanh(v);
                else               Cb[idx] = (bf16)v;
            }
}

// ---------------------------------------------------------------------------
// V transpose: qkv[tok][384+h*64+d] -> vt[bh][d][seq]  (bf16)
// ---------------------------------------------------------------------------
__global__ __launch_bounds__(256) void vtrans_kernel(
    const bf16* __restrict__ qkv, bf16* __restrict__ vt)
{
    __shared__ bf16 t[64][72];
    const int tid = threadIdx.x;
    const int bh = blockIdx.y, b = bh / NH, h = bh % NH;
    const int s0 = blockIdx.x * 64;

#pragma unroll
    for (int i = 0; i < 2; i++) {
        const int chunk = tid + 256 * i;        // 512 chunks of 8 bf16
        const int srow = chunk >> 3, g = chunk & 7;
        *(uint4*)&t[srow][g * 8] =
            *(const uint4*)(qkv + (size_t)(b * SEQ + s0 + srow) * 576 + 384 + h * 64 + g * 8);
    }
    __syncthreads();
#pragma unroll
    for (int i = 0; i < 2; i++) {
        const int chunk = tid + 256 * i;
        const int d = chunk >> 3, sg = chunk & 7;
        bf16x8 v;
#pragma unroll
        for (int j = 0; j < 8; j++) v[j] = t[sg * 8 + j][d];
        *(bf16x8*)(vt + ((size_t)bh * HD + d) * SEQ + s0 + sg * 8) = v;
    }
}

// ---------------------------------------------------------------------------
// MFMA flash attention. Block: 256 thr = 4 waves; wave = 32 queries.
// Grid: (SEQ/128, BATCH*NH). Q/K frags direct global; V from vt[bh][d][seq];
// P via per-wave swizzled LDS.
// ---------------------------------------------------------------------------
__global__ __launch_bounds__(256) void attn_mfma(
    const bf16* __restrict__ qkv, const bf16* __restrict__ vt,
    bf16* __restrict__ obuf)
{
    __shared__ bf16 Ps[4][32 * 64];
    const int tid  = threadIdx.x;
    const int lane = tid & 63, w = tid >> 6;
    const int quad = lane >> 4, c = lane & 15;
    const int bh = blockIdx.y, b = bh / NH, h = bh % NH;
    const int q0 = blockIdx.x * 128 + w * 32;

    bf16* Pw = &Ps[w][0];
    const bf16* kbase = qkv + (size_t)b * SEQ * 576 + 192 + h * 64;
    const bf16* vbase = vt + (size_t)bh * HD * SEQ;

    bf16x8 qf[2][2];
#pragma unroll
    for (int mt = 0; mt < 2; mt++)
#pragma unroll
        for (int ch = 0; ch < 2; ch++)
            qf[mt][ch] = *(const bf16x8*)(qkv + (size_t)(b * SEQ + q0 + mt*16 + c) * 576
                                              + h * 64 + ch * 32 + quad * 8);

    f32x4 of[2][4];
    float mst[2][4], lst[2][4];
#pragma unroll
    for (int mt = 0; mt < 2; mt++)
#pragma unroll
        for (int r = 0; r < 4; r++) {
            mst[mt][r] = -1e30f; lst[mt][r] = 0.f;
        }
#pragma unroll
    for (int mt = 0; mt < 2; mt++)
#pragma unroll
        for (int dt = 0; dt < 4; dt++) of[mt][dt] = (f32x4){0.f, 0.f, 0.f, 0.f};

#pragma unroll 1
    for (int kt = 0; kt < SEQ / 64; kt++) {
        // S = Q K^T  (fp32 accum in C-layout)
        f32x4 sf[2][4];
#pragma unroll
        for (int mt = 0; mt < 2; mt++)
#pragma unroll
            for (int nt = 0; nt < 4; nt++) sf[mt][nt] = (f32x4){0.f, 0.f, 0.f, 0.f};
#pragma unroll
        for (int ch = 0; ch < 2; ch++) {
            bf16x8 kf[4];
#pragma unroll
            for (int nt = 0; nt < 4; nt++)
                kf[nt] = *(const bf16x8*)(kbase + (size_t)(kt*64 + nt*16 + c) * 576
                                               + ch * 32 + quad * 8);
#pragma unroll
            for (int mt = 0; mt < 2; mt++)
#pragma unroll
                for (int nt = 0; nt < 4; nt++)
                    sf[mt][nt] = MFMA16(qf[mt][ch], kf[nt], sf[mt][nt]);
        }

        // online softmax; rows = quad*4+r, reduce across 16 lanes of the quad
        const float sc = 0.125f;   // 1/sqrt(64)
        float alpha[2][4];
#pragma unroll
        for (int mt = 0; mt < 2; mt++)
#pragma unroll
            for (int r = 0; r < 4; r++) {
                float t = fmaxf(fmaxf(sf[mt][0][r], sf[mt][1][r]),
                                fmaxf(sf[mt][2][r], sf[mt][3][r]));
#pragma unroll
                for (int off = 1; off < 16; off <<= 1) t = fmaxf(t, __shfl_xor(t, off));
                t *= sc;
                const float mn = fmaxf(mst[mt][r], t);
                alpha[mt][r] = __expf(mst[mt][r] - mn);
                mst[mt][r] = mn;
                float rs = 0.f;
#pragma unroll
                for (int nt = 0; nt < 4; nt++) {
                    const float p = __expf(sf[mt][nt][r] * sc - mn);
                    sf[mt][nt][r] = p;
                    rs += p;
                }
#pragma unroll
                for (int off = 1; off < 16; off <<= 1) rs += __shfl_xor(rs, off);
                lst[mt][r] = lst[mt][r] * alpha[mt][r] + rs;
#pragma unroll
                for (int dt = 0; dt < 4; dt++) of[mt][dt][r] *= alpha[mt][r];
            }

        // P -> LDS (bf16, row-swizzled)
#pragma unroll
        for (int mt = 0; mt < 2; mt++)
#pragma unroll
            for (int nt = 0; nt < 4; nt++)
#pragma unroll
                for (int r = 0; r < 4; r++) {
                    const int row = mt*16 + quad*4 + r;
                    const int col = nt*16 + c;
                    Pw[row*64 + (((col >> 3) ^ (row & 7)) * 8) + (col & 7)] =
                        (bf16)sf[mt][nt][r];
                }

        // O += P V
#pragma unroll
        for (int ch = 0; ch < 2; ch++) {
            bf16x8 vf[4], pf[2];
#pragma unroll
            for (int dt = 0; dt < 4; dt++)
                vf[dt] = *(const bf16x8*)(vbase + (size_t)(dt*16 + c) * SEQ
                                               + kt*64 + ch*32 + quad*8);
#pragma unroll
            for (int mt = 0; mt < 2; mt++) {
                const int row = mt*16 + c;
                pf[mt] = *(const bf16x8*)(Pw + row*64 + (((ch*4 + quad) ^ (c & 7)) * 8));
            }
#pragma unroll
            for (int mt = 0; mt < 2; mt++)
#pragma unroll
                for (int dt = 0; dt < 4; dt++)
                    of[mt][dt] = MFMA16(pf[mt], vf[dt], of[mt][dt]);
        }
    }

    // epilogue
#pragma unroll
    for (int mt = 0; mt < 2; mt++)
#pragma unroll
        for (int r = 0; r < 4; r++) {
            const float inv = 1.0f / lst[mt][r];
            const size_t tok = (size_t)b * SEQ + q0 + mt*16 + quad*4 + r;
#pragma unroll
            for (int dt = 0; dt < 4; dt++)
                obuf[tok * DIM + h*64 + dt*16 + c] = (bf16)(of[mt][dt][r] * inv);
        }
}

// ---------------------------------------------------------------------------
// LayerNorm over 192 -> bf16, one wave per token
// ---------------------------------------------------------------------------
__global__ __launch_bounds__(64) void ln_kernel(
    const float* __restrict__ X, const float* __restrict__ w,
    const float* __restrict__ bb, bf16* __restrict__ Y)
{
    const int token = blockIdx.x;
    const int lane  = threadIdx.x;
    const float* xt = X + (size_t)token * DIM;
    float v[3];
#pragma unroll
    for (int r = 0; r < 3; r++) v[r] = xt[lane + 64 * r];
    float sum = v[0] + v[1] + v[2];
#pragma unroll
    for (int off = 32; off; off >>= 1) sum += __shfl_xor(sum, off);
    const float mean = sum / (float)DIM;
    float vs = (v[0]-mean)*(v[0]-mean) + (v[1]-mean)*(v[1]-mean) + (v[2]-mean)*(v[2]-mean);
#pragma unroll
    for (int off = 32; off; off >>= 1) vs += __shfl_xor(vs, off);
    const float inv = rsqrtf(vs / (float)DIM + 1e-5f);
    bf16* yt = Y + (size_t)token * DIM;
#pragma unroll
    for (int r = 0; r < 3; r++) {
        const int d = lane + 64 * r;
        yt[d] = (bf16)((v[r] - mean) * inv * w[d] + bb[d]);
    }
}

// ---------------------------------------------------------------------------
// Final: out[token, i, d] += y[token, d] * hpost[token, i]
// ---------------------------------------------------------------------------
__global__ __launch_bounds__(256) void final_kernel(
    const float* __restrict__ y, const float* __restrict__ hpost,
    float* __restrict__ out)
{
    const size_t g = (size_t)blockIdx.x * blockDim.x + threadIdx.x;
    if (g >= (size_t)TOKENS * (ND / 4)) return;
    const int token = (int)(g / (ND / 4));
    const int f     = (int)(g % (ND / 4));
    const int i     = f / (DIM / 4);
    const int d4    = f % (DIM / 4);
    const float4 yv = ((const float4*)(y + (size_t)token * DIM))[d4];
    const float hp  = hpost[(size_t)token * NS + i];
    float4* op = (float4*)out + g;
    float4 ov = *op;
    ov.x += yv.x * hp; ov.y += yv.y * hp; ov.z += yv.z * hp; ov.w += yv.w * hp;
    *op = ov;
}

// ---------------------------------------------------------------------------
extern "C" void kernel_launch(void* const* d_in, const int* in_sizes, int n_in,
                              void* d_out, int out_size, void* d_ws, size_t ws_size,
                              hipStream_t stream) {
    const float* x         = (const float*)d_in[0];
    const float* norm_w    = (const float*)d_in[1];
    const float* phi_pre   = (const float*)d_in[2];
    const float* phi_post  = (const float*)d_in[3];
    const float* phi_res   = (const float*)d_in[4];
    const float* b_pre     = (const float*)d_in[5];
    const float* b_post    = (const float*)d_in[6];
    const float* b_res     = (const float*)d_in[7];
    const float* alpha_pre = (const float*)d_in[8];
    const float* alpha_post= (const float*)d_in[9];
    const float* alpha_res = (const float*)d_in[10];
    const float* ln1_w     = (const float*)d_in[11];
    const float* ln1_b     = (const float*)d_in[12];
    const float* Wq        = (const float*)d_in[13];
    const float* Wk        = (const float*)d_in[14];
    const float* Wv        = (const float*)d_in[15];
    const float* Wo        = (const float*)d_in[16];
    const float* ln2_w     = (const float*)d_in[17];
    const float* ln2_b     = (const float*)d_in[18];
    const float* W1        = (const float*)d_in[19];
    const float* W2        = (const float*)d_in[20];

    float* out = (float*)d_out;
    float* ws  = (float*)d_ws;

    // Workspace carve (floats). Total ~31.8M floats = 127 MB.
    const size_t TBf = (size_t)TOKENS * DIM;     // 6,291,456
    float* xin   = ws;                           // fp32 [TB]
    float* x1    = ws + TBf;                     // fp32 [TB]
    float* hpost = ws + 2 * TBf;                 // fp32 [TOKENS*4]
    bf16*  wqkv  = (bf16*)(ws + 2 * TBf + 131072);          // [576][192]
    bf16*  wot   = wqkv + 576 * 192;                        // [192][192]
    bf16*  w1t   = wot + 192 * 192;                         // [768][192]
    bf16*  w2t   = w1t + 768 * 192;                         // [192][768]
    float* regAC = ws + 2 * TBf + 131072 + 221184;
    bf16*  qkv   = (bf16*)regAC;                 // [32768][576]
    bf16*  vt    = qkv + (size_t)TOKENS * 576;   // [96][64][1024]
    bf16*  gbuf  = (bf16*)regAC;                 // [32768][768] (aliases qkv+vt)
    float* regBD = regAC + 12582912;
    bf16*  h1    = (bf16*)regBD;                 // [32768][192]
    bf16*  obuf  = h1;                           // alias (h1 dead after QKV)
    bf16*  h2    = h1 + TBf;                     // [32768][192]
    float* ybuf  = regBD;                        // fp32 [TB] (aliases h1+h2)

    // 0. weight convert/transpose
    {
        dim3 blk(32, 8);
        wconv_kernel<<<dim3(192/32, 192/32), blk, 0, stream>>>(Wq, wqkv,             192, 192);
        wconv_kernel<<<dim3(192/32, 192/32), blk, 0, stream>>>(Wk, wqkv + 192*192,   192, 192);
        wconv_kernel<<<dim3(192/32, 192/32), blk, 0, stream>>>(Wv, wqkv + 2*192*192, 192, 192);
        wconv_kernel<<<dim3(192/32, 192/32), blk, 0, stream>>>(Wo, wot,              192, 192);
        wconv_kernel<<<dim3(768/32, 192/32), blk, 0, stream>>>(W1, w1t,              192, 768);
        wconv_kernel<<<dim3(192/32, 768/32), blk, 0, stream>>>(W2, w2t,              768, 192);
    }

    // 1. gating
    gating_kernel<<<TOKENS, 64, 0, stream>>>(
        x, norm_w, phi_pre, phi_post, phi_res, b_pre, b_post, b_res,
        alpha_pre, alpha_post, alpha_res, ln1_w, ln1_b,
        out, xin, h1, hpost);

    // 2. fused QKV projection: [32768,192] @ [192,576] -> qkv bf16
    mfma_gemm<0><<<dim3(576/64, TOKENS/128), 256, 0, stream>>>(
        h1, wqkv, nullptr, nullptr, qkv, TOKENS, 576, 192);

    // 3. V transpose
    vtrans_kernel<<<dim3(SEQ/64, BATCH*NH), 256, 0, stream>>>(qkv, vt);

    // 4. attention -> obuf bf16
    attn_mfma<<<dim3(SEQ/128, BATCH*NH), 256, 0, stream>>>(qkv, vt, obuf);

    // 5. x1 = xin + obuf @ Wo  (fp32)
    mfma_gemm<1><<<dim3(192/64, TOKENS/128), 256, 0, stream>>>(
        obuf, wot, xin, x1, nullptr, TOKENS, 192, 192);

    // 6. h2 = LN2(x1) bf16
    ln_kernel<<<TOKENS, 64, 0, stream>>>(x1, ln2_w, ln2_b, h2);

    // 7. g = gelu(h2 @ W1) bf16
    mfma_gemm<2><<<dim3(768/64, TOKENS/128), 256, 0, stream>>>(
        h2, w1t, nullptr, nullptr, gbuf, TOKENS, 768, 192);

    // 8. y = x1 + g @ W2 (fp32)
    mfma_gemm<1><<<dim3(192/64, TOKENS/128), 256, 0, stream>>>(
        gbuf, w2t, x1, ybuf, nullptr, TOKENS, 192, 768);

    // 9. out += y * h_post
    {
        const int n4 = TOKENS * (ND / 4);
        final_kernel<<<(n4 + 255) / 256, 256, 0, stream>>>(ybuf, hpost, out);
    }
}

// Round 4
// 697.564 us; speedup vs baseline: 12.9023x; 1.2807x over previous
//
#include <hip/hip_runtime.h>
#include <hip/hip_bf16.h>
#include <math.h>

// Problem constants
#define BATCH 32
#define SEQ   1024
#define NS    4
#define DIM   192
#define ND    768
#define NH    3
#define HD    64
#define MLP   768
#define TOKENS (BATCH*SEQ)   // 32768

typedef __bf16 bf16;
typedef bf16  bf16x8 __attribute__((ext_vector_type(8)));
typedef bf16  bf16x4 __attribute__((ext_vector_type(4)));
typedef float f32x4  __attribute__((ext_vector_type(4)));

#define MFMA16(a,b,c) __builtin_amdgcn_mfma_f32_16x16x32_bf16(a,b,c,0,0,0)

__device__ inline float gelu_tanh(float x) {
    float x3 = x * x * x;
    return 0.5f * x * (1.0f + tanhf(0.7978845608028654f * (x + 0.044715f * x3)));
}

// ---------------------------------------------------------------------------
// Weight convert + transpose (+scale): dst[N][K] (bf16) = scale * src[K][N]
// ---------------------------------------------------------------------------
__global__ __launch_bounds__(256) void wconv_kernel(
    const float* __restrict__ src, bf16* __restrict__ dst, int K, int N,
    float scale)
{
    __shared__ float t[32][33];
    const int x = threadIdx.x, y = threadIdx.y;     // 32 x 8
    const int k0 = blockIdx.y * 32, n0 = blockIdx.x * 32;
#pragma unroll
    for (int i = 0; i < 4; i++)
        t[y + 8*i][x] = src[(size_t)(k0 + y + 8*i) * N + n0 + x];
    __syncthreads();
#pragma unroll
    for (int i = 0; i < 4; i++)
        dst[(size_t)(n0 + y + 8*i) * K + k0 + x] = (bf16)(scale * t[x][y + 8*i]);
}

// ---------------------------------------------------------------------------
// phi' build: phiw[n][k] = norm_w[k] * phi_cat[k][n], n in [0,32) (24..31 = 0)
// ---------------------------------------------------------------------------
__global__ __launch_bounds__(256) void phiw_kernel(
    const float* __restrict__ nw, const float* __restrict__ ppre,
    const float* __restrict__ ppost, const float* __restrict__ pres,
    bf16* __restrict__ phiw)
{
    const int k = blockIdx.x * 256 + threadIdx.x;
    if (k >= ND) return;
    const float w = nw[k];
#pragma unroll
    for (int n = 0; n < 4; n++)  phiw[n * ND + k]       = (bf16)(w * ppre[k*4 + n]);
#pragma unroll
    for (int n = 0; n < 4; n++)  phiw[(4+n) * ND + k]   = (bf16)(w * ppost[k*4 + n]);
#pragma unroll
    for (int n = 0; n < 16; n++) phiw[(8+n) * ND + k]   = (bf16)(w * pres[k*16 + n]);
#pragma unroll
    for (int n = 24; n < 32; n++) phiw[n * ND + k]      = (bf16)0.f;
}

// ---------------------------------------------------------------------------
// prep: one wave per token. rinv[t] = rsqrt(mean(x^2)+eps); xb = bf16(x)
// ---------------------------------------------------------------------------
__global__ __launch_bounds__(64) void prep_kernel(
    const float* __restrict__ x, bf16* __restrict__ xb, float* __restrict__ rinv)
{
    const int tok = blockIdx.x, lane = threadIdx.x;
    const float* xt = x + (size_t)tok * ND;
    float4 xv[3];
    float ssq = 0.f;
#pragma unroll
    for (int r = 0; r < 3; r++) {
        xv[r] = ((const float4*)xt)[lane + 64 * r];
        ssq += xv[r].x*xv[r].x + xv[r].y*xv[r].y + xv[r].z*xv[r].z + xv[r].w*xv[r].w;
    }
#pragma unroll
    for (int off = 32; off; off >>= 1) ssq += __shfl_xor(ssq, off);
    if (lane == 0) rinv[tok] = rsqrtf(ssq / (float)ND + 1e-8f);
#pragma unroll
    for (int r = 0; r < 3; r++) {
        bf16x4 o = {(bf16)xv[r].x, (bf16)xv[r].y, (bf16)xv[r].z, (bf16)xv[r].w};
        *(bf16x4*)(xb + (size_t)tok * ND + 4 * (lane + 64 * r)) = o;
    }
}

// ---------------------------------------------------------------------------
// dots: MFMA GEMM  dots[t][n] = rinv[t] * (xb[t][:] . phiw[n][:])
// Block 256 = 4 waves; wave handles 16 tokens; N = 32 (2 n-tiles).
// ---------------------------------------------------------------------------
__global__ __launch_bounds__(256) void dots_kernel(
    const bf16* __restrict__ xb, const bf16* __restrict__ phiw,
    const float* __restrict__ rinv, float* __restrict__ dots)
{
    const int tid = threadIdx.x, lane = tid & 63, w = tid >> 6;
    const int quad = lane >> 4, c = lane & 15;
    const int tok0 = blockIdx.x * 64 + w * 16;

    f32x4 acc0 = {0.f,0.f,0.f,0.f}, acc1 = {0.f,0.f,0.f,0.f};
    const bf16* arow = xb + (size_t)(tok0 + c) * ND + quad * 8;
    const bf16* b0   = phiw + (size_t)c * ND + quad * 8;
    const bf16* b1   = phiw + (size_t)(16 + c) * ND + quad * 8;
#pragma unroll 6
    for (int k0 = 0; k0 < ND; k0 += 32) {
        bf16x8 af  = *(const bf16x8*)(arow + k0);
        bf16x8 bf0 = *(const bf16x8*)(b0 + k0);
        bf16x8 bf1 = *(const bf16x8*)(b1 + k0);
        acc0 = MFMA16(af, bf0, acc0);
        acc1 = MFMA16(af, bf1, acc1);
    }
#pragma unroll
    for (int r = 0; r < 4; r++) {
        const int tok = tok0 + quad * 4 + r;
        const float s = rinv[tok];
        dots[(size_t)tok * 32 + c]      = acc0[r] * s;
        dots[(size_t)tok * 32 + 16 + c] = acc1[r] * s;
    }
}

// ---------------------------------------------------------------------------
// sink: ONE LANE PER TOKEN. sigmoid gates + 20-iter 4x4 sinkhorn, all regs.
// hgate[t][20] = {hres[16], hpre[4]}; hpost[t][4].
// ---------------------------------------------------------------------------
__global__ __launch_bounds__(256) void sink_kernel(
    const float* __restrict__ dots, const float* __restrict__ b_pre,
    const float* __restrict__ b_post, const float* __restrict__ b_res,
    const float* __restrict__ a_pre, const float* __restrict__ a_post,
    const float* __restrict__ a_res,
    float* __restrict__ hgate, float* __restrict__ hpost)
{
    const int tok = blockIdx.x * 256 + threadIdx.x;
    const float* dt = dots + (size_t)tok * 32;
    float d[24];
#pragma unroll
    for (int i = 0; i < 6; i++) *(float4*)&d[i*4] = *(const float4*)(dt + i*4);

    const float apre = a_pre[0], apost = a_post[0], ares = a_res[0];
    float hpre[4], hpo[4], m[16];
#pragma unroll
    for (int i = 0; i < 4; i++) {
        hpre[i] = 1.f / (1.f + __expf(-(apre  * d[i]     + b_pre[i])));
        hpo[i]  = 2.f / (1.f + __expf(-(apost * d[4 + i] + b_post[i])));
    }
#pragma unroll
    for (int p = 0; p < 16; p++) m[p] = ares * d[8 + p] + b_res[p];

    float gm = m[0];
#pragma unroll
    for (int p = 1; p < 16; p++) gm = fmaxf(gm, m[p]);
#pragma unroll
    for (int p = 0; p < 16; p++) m[p] = __expf(m[p] - gm);

    for (int it = 0; it < 20; it++) {
#pragma unroll
        for (int i = 0; i < 4; i++) {
            const float inv = 1.f / (m[i*4+0] + m[i*4+1] + m[i*4+2] + m[i*4+3] + 1e-8f);
#pragma unroll
            for (int j = 0; j < 4; j++) m[i*4+j] *= inv;
        }
#pragma unroll
        for (int j = 0; j < 4; j++) {
            const float inv = 1.f / (m[0*4+j] + m[1*4+j] + m[2*4+j] + m[3*4+j] + 1e-8f);
#pragma unroll
            for (int i = 0; i < 4; i++) m[i*4+j] *= inv;
        }
    }

    float* hg = hgate + (size_t)tok * 20;
#pragma unroll
    for (int i = 0; i < 4; i++) *(float4*)(hg + i*4) = *(float4*)&m[i*4];
    *(float4*)(hg + 16) = *(float4*)hpre;
    *(float4*)(hpost + (size_t)tok * 4) = *(float4*)hpo;
}

// ---------------------------------------------------------------------------
// mix: one wave per token. out = hres @ x (x_res), xin = hpre . x,
// h1 = LN1(xin) bf16. hgate read is wave-uniform (s_load).
// ---------------------------------------------------------------------------
__global__ __launch_bounds__(64) void mix_kernel(
    const bf16* __restrict__ xb, const float* __restrict__ hgate,
    const float* __restrict__ ln1_w, const float* __restrict__ ln1_b,
    float* __restrict__ out, float* __restrict__ xin, bf16* __restrict__ h1)
{
    const int tok = blockIdx.x, lane = threadIdx.x;
    __shared__ float ldsx[ND];

    const bf16* xt = xb + (size_t)tok * ND;
#pragma unroll
    for (int r = 0; r < 3; r++) {
        const bf16x4 v = *(const bf16x4*)(xt + 4 * (lane + 64 * r));
        float4 f = {(float)v[0], (float)v[1], (float)v[2], (float)v[3]};
        ((float4*)ldsx)[lane + 64 * r] = f;
    }

    const float* hg = hgate + (size_t)tok * 20;
    float hres[16], hpre[4];
#pragma unroll
    for (int p = 0; p < 16; p++) hres[p] = hg[p];
#pragma unroll
    for (int i = 0; i < 4; i++) hpre[i] = hg[16 + i];

    __syncthreads();

    float* ot = out + (size_t)tok * ND;
#pragma unroll
    for (int r = 0; r < 3; r++) {
        const int g  = lane + 64 * r;
        const int p0 = 4 * g;
        const int i  = p0 / DIM;
        const int d0 = p0 % DIM;
        float4 o;
        o.x = hres[i*4+0]*ldsx[0*DIM+d0+0] + hres[i*4+1]*ldsx[1*DIM+d0+0]
            + hres[i*4+2]*ldsx[2*DIM+d0+0] + hres[i*4+3]*ldsx[3*DIM+d0+0];
        o.y = hres[i*4+0]*ldsx[0*DIM+d0+1] + hres[i*4+1]*ldsx[1*DIM+d0+1]
            + hres[i*4+2]*ldsx[2*DIM+d0+1] + hres[i*4+3]*ldsx[3*DIM+d0+1];
        o.z = hres[i*4+0]*ldsx[0*DIM+d0+2] + hres[i*4+1]*ldsx[1*DIM+d0+2]
            + hres[i*4+2]*ldsx[2*DIM+d0+2] + hres[i*4+3]*ldsx[3*DIM+d0+2];
        o.w = hres[i*4+0]*ldsx[0*DIM+d0+3] + hres[i*4+1]*ldsx[1*DIM+d0+3]
            + hres[i*4+2]*ldsx[2*DIM+d0+3] + hres[i*4+3]*ldsx[3*DIM+d0+3];
        ((float4*)ot)[g] = o;
    }

    float xi[3];
#pragma unroll
    for (int r = 0; r < 3; r++) {
        const int d = lane + 64 * r;
        xi[r] = hpre[0]*ldsx[d] + hpre[1]*ldsx[DIM+d]
              + hpre[2]*ldsx[2*DIM+d] + hpre[3]*ldsx[3*DIM+d];
    }
    float sum = xi[0] + xi[1] + xi[2];
#pragma unroll
    for (int off = 32; off; off >>= 1) sum += __shfl_xor(sum, off);
    const float mean = sum / (float)DIM;
    float vs = (xi[0]-mean)*(xi[0]-mean) + (xi[1]-mean)*(xi[1]-mean) + (xi[2]-mean)*(xi[2]-mean);
#pragma unroll
    for (int off = 32; off; off >>= 1) vs += __shfl_xor(vs, off);
    const float inv = rsqrtf(vs / (float)DIM + 1e-5f);

    float* xint = xin + (size_t)tok * DIM;
    bf16*  ht   = h1  + (size_t)tok * DIM;
#pragma unroll
    for (int r = 0; r < 3; r++) {
        const int d = lane + 64 * r;
        xint[d] = xi[r];
        ht[d]   = (bf16)((xi[r] - mean) * inv * ln1_w[d] + ln1_b[d]);
    }
}

// ---------------------------------------------------------------------------
// bf16 MFMA GEMM: C[M,N] = epi(A[M,K] @ Bt[N,K]^T [+R])
// 128x64 tile, BK=64, 256 threads (4 waves). XOR-swizzled LDS.
// EPI: 0 = bf16 out, 1 = +R fp32 out, 2 = gelu bf16 out
// ---------------------------------------------------------------------------
template<int EPI>
__global__ __launch_bounds__(256) void mfma_gemm(
    const bf16* __restrict__ A, const bf16* __restrict__ Bt,
    const float* __restrict__ R, float* __restrict__ Cf, bf16* __restrict__ Cb,
    int M, int N, int K)
{
    __shared__ bf16 As[128 * 64];
    __shared__ bf16 Bs[64 * 64];
    const int tid  = threadIdx.x;
    const int lane = tid & 63, w = tid >> 6;
    const int quad = lane >> 4, c = lane & 15;
    const int m0 = blockIdx.y * 128, n0 = blockIdx.x * 64;
    const int wm = (w >> 1) * 64, wn = (w & 1) * 32;

    int sa[4], sb[2];
    size_t aoff[4], boff[2];
#pragma unroll
    for (int j = 0; j < 4; j++) {
        sa[j] = (w * 4 + j) * 64 + lane;
        const int m = sa[j] >> 3, gp = sa[j] & 7;
        const int g = gp ^ (m & 7);
        aoff[j] = (size_t)(m0 + m) * K + g * 8;
    }
#pragma unroll
    for (int j = 0; j < 2; j++) {
        sb[j] = (w * 2 + j) * 64 + lane;
        const int n = sb[j] >> 3, gp = sb[j] & 7;
        const int g = gp ^ (n & 7);
        boff[j] = (size_t)(n0 + n) * K + g * 8;
    }

    f32x4 acc[4][2];
#pragma unroll
    for (int i = 0; i < 4; i++)
#pragma unroll
        for (int j = 0; j < 2; j++) acc[i][j] = (f32x4){0.f, 0.f, 0.f, 0.f};

    for (int k0 = 0; k0 < K; k0 += 64) {
        uint4 av[4], bv[2];
#pragma unroll
        for (int j = 0; j < 4; j++) av[j] = *(const uint4*)(A + aoff[j] + k0);
#pragma unroll
        for (int j = 0; j < 2; j++) bv[j] = *(const uint4*)(Bt + boff[j] + k0);
        __syncthreads();
#pragma unroll
        for (int j = 0; j < 4; j++) *(uint4*)(As + sa[j] * 8) = av[j];
#pragma unroll
        for (int j = 0; j < 2; j++) *(uint4*)(Bs + sb[j] * 8) = bv[j];
        __syncthreads();
#pragma unroll
        for (int ch = 0; ch < 2; ch++) {
            bf16x8 af[4], bfr[2];
#pragma unroll
            for (int mt = 0; mt < 4; mt++)
                af[mt] = *(const bf16x8*)(As + (wm + mt*16 + c) * 64
                                             + (((ch*4 + quad) ^ (c & 7)) * 8));
#pragma unroll
            for (int nt = 0; nt < 2; nt++)
                bfr[nt] = *(const bf16x8*)(Bs + (wn + nt*16 + c) * 64
                                              + (((ch*4 + quad) ^ (c & 7)) * 8));
#pragma unroll
            for (int mt = 0; mt < 4; mt++)
#pragma unroll
                for (int nt = 0; nt < 2; nt++)
                    acc[mt][nt] = MFMA16(af[mt], bfr[nt], acc[mt][nt]);
        }
    }

#pragma unroll
    for (int mt = 0; mt < 4; mt++)
#pragma unroll
        for (int nt = 0; nt < 2; nt++)
#pragma unroll
            for (int r = 0; r < 4; r++) {
                const int row = m0 + wm + mt*16 + quad*4 + r;
                const int col = n0 + wn + nt*16 + c;
                const size_t idx = (size_t)row * N + col;
                float v = acc[mt][nt][r];
                if (EPI == 1)      Cf[idx] = v + R[idx];
                else if (EPI == 2) Cb[idx] = (bf16)gelu_tanh(v);
                else               Cb[idx] = (bf16)v;
            }
}

// ---------------------------------------------------------------------------
// V transpose: qkv[tok][384+h*64+d] -> vt[bh][d][seq]  (bf16)
// ---------------------------------------------------------------------------
__global__ __launch_bounds__(256) void vtrans_kernel(
    const bf16* __restrict__ qkv, bf16* __restrict__ vt)
{
    __shared__ bf16 t[64][72];
    const int tid = threadIdx.x;
    const int bh = blockIdx.y, b = bh / NH, h = bh % NH;
    const int s0 = blockIdx.x * 64;

#pragma unroll
    for (int i = 0; i < 2; i++) {
        const int chunk = tid + 256 * i;
        const int srow = chunk >> 3, g = chunk & 7;
        *(uint4*)&t[srow][g * 8] =
            *(const uint4*)(qkv + (size_t)(b * SEQ + s0 + srow) * 576 + 384 + h * 64 + g * 8);
    }
    __syncthreads();
#pragma unroll
    for (int i = 0; i < 2; i++) {
        const int chunk = tid + 256 * i;
        const int d = chunk >> 3, sg = chunk & 7;
        bf16x8 v;
#pragma unroll
        for (int j = 0; j < 8; j++) v[j] = t[sg * 8 + j][d];
        *(bf16x8*)(vt + ((size_t)bh * HD + d) * SEQ + s0 + sg * 8) = v;
    }
}

// ---------------------------------------------------------------------------
// MFMA flash attention, NO max-shift (scores bounded; 1/8 folded into Wq).
// Block: 256 thr = 4 waves; wave = 32 queries. Grid: (SEQ/128, BATCH*NH).
// ---------------------------------------------------------------------------
__global__ __launch_bounds__(256) void attn_mfma(
    const bf16* __restrict__ qkv, const bf16* __restrict__ vt,
    bf16* __restrict__ obuf)
{
    __shared__ bf16 Ps[4][32 * 64];
    const int tid  = threadIdx.x;
    const int lane = tid & 63, w = tid >> 6;
    const int quad = lane >> 4, c = lane & 15;
    const int bh = blockIdx.y, b = bh / NH, h = bh % NH;
    const int q0 = blockIdx.x * 128 + w * 32;

    bf16* Pw = &Ps[w][0];
    const bf16* kbase = qkv + (size_t)b * SEQ * 576 + 192 + h * 64;
    const bf16* vbase = vt + (size_t)bh * HD * SEQ;

    bf16x8 qf[2][2];
#pragma unroll
    for (int mt = 0; mt < 2; mt++)
#pragma unroll
        for (int ch = 0; ch < 2; ch++)
            qf[mt][ch] = *(const bf16x8*)(qkv + (size_t)(b * SEQ + q0 + mt*16 + c) * 576
                                              + h * 64 + ch * 32 + quad * 8);

    f32x4 of[2][4];
    float lst[2][4];
#pragma unroll
    for (int mt = 0; mt < 2; mt++)
#pragma unroll
        for (int r = 0; r < 4; r++) lst[mt][r] = 0.f;
#pragma unroll
    for (int mt = 0; mt < 2; mt++)
#pragma unroll
        for (int dt = 0; dt < 4; dt++) of[mt][dt] = (f32x4){0.f, 0.f, 0.f, 0.f};

#pragma unroll 1
    for (int kt = 0; kt < SEQ / 64; kt++) {
        // S = Q K^T (already includes 1/sqrt(hd) via Wq scaling)
        f32x4 sf[2][4];
#pragma unroll
        for (int mt = 0; mt < 2; mt++)
#pragma unroll
            for (int nt = 0; nt < 4; nt++) sf[mt][nt] = (f32x4){0.f, 0.f, 0.f, 0.f};
#pragma unroll
        for (int ch = 0; ch < 2; ch++) {
            bf16x8 kf[4];
#pragma unroll
            for (int nt = 0; nt < 4; nt++)
                kf[nt] = *(const bf16x8*)(kbase + (size_t)(kt*64 + nt*16 + c) * 576
                                               + ch * 32 + quad * 8);
#pragma unroll
            for (int mt = 0; mt < 2; mt++)
#pragma unroll
                for (int nt = 0; nt < 4; nt++)
                    sf[mt][nt] = MFMA16(qf[mt][ch], kf[nt], sf[mt][nt]);
        }

        // exp + row-sum (no max-shift)
#pragma unroll
        for (int mt = 0; mt < 2; mt++)
#pragma unroll
            for (int r = 0; r < 4; r++) {
                float rs = 0.f;
#pragma unroll
                for (int nt = 0; nt < 4; nt++) {
                    const float p = __expf(sf[mt][nt][r]);
                    sf[mt][nt][r] = p;
                    rs += p;
                }
#pragma unroll
                for (int off = 1; off < 16; off <<= 1) rs += __shfl_xor(rs, off);
                lst[mt][r] += rs;
            }

        // P -> LDS (bf16, row-swizzled)
#pragma unroll
        for (int mt = 0; mt < 2; mt++)
#pragma unroll
            for (int nt = 0; nt < 4; nt++)
#pragma unroll
                for (int r = 0; r < 4; r++) {
                    const int row = mt*16 + quad*4 + r;
                    const int col = nt*16 + c;
                    Pw[row*64 + (((col >> 3) ^ (row & 7)) * 8) + (col & 7)] =
                        (bf16)sf[mt][nt][r];
                }

        // O += P V
#pragma unroll
        for (int ch = 0; ch < 2; ch++) {
            bf16x8 vf[4], pf[2];
#pragma unroll
            for (int dt = 0; dt < 4; dt++)
                vf[dt] = *(const bf16x8*)(vbase + (size_t)(dt*16 + c) * SEQ
                                               + kt*64 + ch*32 + quad*8);
#pragma unroll
            for (int mt = 0; mt < 2; mt++) {
                const int row = mt*16 + c;
                pf[mt] = *(const bf16x8*)(Pw + row*64 + (((ch*4 + quad) ^ (c & 7)) * 8));
            }
#pragma unroll
            for (int mt = 0; mt < 2; mt++)
#pragma unroll
                for (int dt = 0; dt < 4; dt++)
                    of[mt][dt] = MFMA16(pf[mt], vf[dt], of[mt][dt]);
        }
    }

    // epilogue
#pragma unroll
    for (int mt = 0; mt < 2; mt++)
#pragma unroll
        for (int r = 0; r < 4; r++) {
            const float inv = 1.0f / lst[mt][r];
            const size_t tok = (size_t)b * SEQ + q0 + mt*16 + quad*4 + r;
#pragma unroll
            for (int dt = 0; dt < 4; dt++)
                obuf[tok * DIM + h*64 + dt*16 + c] = (bf16)(of[mt][dt][r] * inv);
        }
}

// ---------------------------------------------------------------------------
// LayerNorm over 192 -> bf16, one wave per token
// ---------------------------------------------------------------------------
__global__ __launch_bounds__(64) void ln_kernel(
    const float* __restrict__ X, const float* __restrict__ w,
    const float* __restrict__ bb, bf16* __restrict__ Y)
{
    const int token = blockIdx.x;
    const int lane  = threadIdx.x;
    const float* xt = X + (size_t)token * DIM;
    float v[3];
#pragma unroll
    for (int r = 0; r < 3; r++) v[r] = xt[lane + 64 * r];
    float sum = v[0] + v[1] + v[2];
#pragma unroll
    for (int off = 32; off; off >>= 1) sum += __shfl_xor(sum, off);
    const float mean = sum / (float)DIM;
    float vs = (v[0]-mean)*(v[0]-mean) + (v[1]-mean)*(v[1]-mean) + (v[2]-mean)*(v[2]-mean);
#pragma unroll
    for (int off = 32; off; off >>= 1) vs += __shfl_xor(vs, off);
    const float inv = rsqrtf(vs / (float)DIM + 1e-5f);
    bf16* yt = Y + (size_t)token * DIM;
#pragma unroll
    for (int r = 0; r < 3; r++) {
        const int d = lane + 64 * r;
        yt[d] = (bf16)((v[r] - mean) * inv * w[d] + bb[d]);
    }
}

// ---------------------------------------------------------------------------
// Final: out[token, i, d] += y[token, d] * hpost[token, i]
// ---------------------------------------------------------------------------
__global__ __launch_bounds__(256) void final_kernel(
    const float* __restrict__ y, const float* __restrict__ hpost,
    float* __restrict__ out)
{
    const size_t g = (size_t)blockIdx.x * blockDim.x + threadIdx.x;
    if (g >= (size_t)TOKENS * (ND / 4)) return;
    const int token = (int)(g / (ND / 4));
    const int f     = (int)(g % (ND / 4));
    const int i     = f / (DIM / 4);
    const int d4    = f % (DIM / 4);
    const float4 yv = ((const float4*)(y + (size_t)token * DIM))[d4];
    const float hp  = hpost[(size_t)token * NS + i];
    float4* op = (float4*)out + g;
    float4 ov = *op;
    ov.x += yv.x * hp; ov.y += yv.y * hp; ov.z += yv.z * hp; ov.w += yv.w * hp;
    *op = ov;
}

// ---------------------------------------------------------------------------
extern "C" void kernel_launch(void* const* d_in, const int* in_sizes, int n_in,
                              void* d_out, int out_size, void* d_ws, size_t ws_size,
                              hipStream_t stream) {
    const float* x         = (const float*)d_in[0];
    const float* norm_w    = (const float*)d_in[1];
    const float* phi_pre   = (const float*)d_in[2];
    const float* phi_post  = (const float*)d_in[3];
    const float* phi_res   = (const float*)d_in[4];
    const float* b_pre     = (const float*)d_in[5];
    const float* b_post    = (const float*)d_in[6];
    const float* b_res     = (const float*)d_in[7];
    const float* alpha_pre = (const float*)d_in[8];
    const float* alpha_post= (const float*)d_in[9];
    const float* alpha_res = (const float*)d_in[10];
    const float* ln1_w     = (const float*)d_in[11];
    const float* ln1_b     = (const float*)d_in[12];
    const float* Wq        = (const float*)d_in[13];
    const float* Wk        = (const float*)d_in[14];
    const float* Wv        = (const float*)d_in[15];
    const float* Wo        = (const float*)d_in[16];
    const float* ln2_w     = (const float*)d_in[17];
    const float* ln2_b     = (const float*)d_in[18];
    const float* W1        = (const float*)d_in[19];
    const float* W2        = (const float*)d_in[20];

    float* out = (float*)d_out;
    float* ws  = (float*)d_ws;

    // ---- workspace carve (float units; every base 16B-aligned) ----
    const size_t TBf = (size_t)TOKENS * DIM;        // 6,291,456
    float* xin   = ws;                               // fp32 [TBf]
    float* x1    = ws + TBf;                         // fp32 [TBf]
    float* hpost = ws + 2 * TBf;                     // fp32 [131072]
    float* rinv  = hpost + 131072;                   // fp32 [32768]
    bf16*  phiw  = (bf16*)(rinv + 32768);            // [32][768]
    bf16*  wqkv  = phiw + 32 * ND;                   // [576][192]
    bf16*  wot   = wqkv + 576 * 192;                 // [192][192]
    bf16*  w1t   = wot + 192 * 192;                  // [768][192]
    bf16*  w2t   = w1t + 768 * 192;                  // [192][768]
    float* regAC = (float*)(w2t + 192 * 768);
    bf16*  xb    = (bf16*)regAC;                     // [32768][768] (dead after mix)
    bf16*  qkv   = (bf16*)regAC;                     // [32768][576]
    bf16*  vt    = qkv + (size_t)TOKENS * 576;       // [96][64][1024]
    bf16*  gbuf  = (bf16*)regAC;                     // [32768][768]
    float* regBD = regAC + 12582912;
    bf16*  h1    = (bf16*)regBD;                     // [32768][192]
    bf16*  obuf  = h1;                               // alias (h1 dead after QKV)
    bf16*  h2    = h1 + TBf;                         // [32768][192] (written at ln)
    float* dotsb = regBD + TBf / 2;                  // fp32 [32768][32] (h2 slot, dead before ln)
    float* hgate = dotsb + (size_t)TOKENS * 32;      // fp32 [32768][20]
    float* ybuf  = regBD;                            // fp32 [TBf] (after h1/h2 dead)

    // 0. weight prep (1/sqrt(64) folded into Wq — exact, power of two)
    {
        dim3 blk(32, 8);
        wconv_kernel<<<dim3(6, 6), blk, 0, stream>>>(Wq, wqkv,             192, 192, 0.125f);
        wconv_kernel<<<dim3(6, 6), blk, 0, stream>>>(Wk, wqkv + 192*192,   192, 192, 1.f);
        wconv_kernel<<<dim3(6, 6), blk, 0, stream>>>(Wv, wqkv + 2*192*192, 192, 192, 1.f);
        wconv_kernel<<<dim3(6, 6), blk, 0, stream>>>(Wo, wot,              192, 192, 1.f);
        wconv_kernel<<<dim3(24, 6), blk, 0, stream>>>(W1, w1t,             192, 768, 1.f);
        wconv_kernel<<<dim3(6, 24), blk, 0, stream>>>(W2, w2t,             768, 192, 1.f);
        phiw_kernel<<<3, 256, 0, stream>>>(norm_w, phi_pre, phi_post, phi_res, phiw);
    }

    // 1. gating pipeline
    prep_kernel<<<TOKENS, 64, 0, stream>>>(x, xb, rinv);
    dots_kernel<<<TOKENS / 64, 256, 0, stream>>>(xb, phiw, rinv, dotsb);
    sink_kernel<<<TOKENS / 256, 256, 0, stream>>>(
        dotsb, b_pre, b_post, b_res, alpha_pre, alpha_post, alpha_res, hgate, hpost);
    mix_kernel<<<TOKENS, 64, 0, stream>>>(xb, hgate, ln1_w, ln1_b, out, xin, h1);

    // 2. fused QKV projection
    mfma_gemm<0><<<dim3(576/64, TOKENS/128), 256, 0, stream>>>(
        h1, wqkv, nullptr, nullptr, qkv, TOKENS, 576, 192);

    // 3. V transpose
    vtrans_kernel<<<dim3(SEQ/64, BATCH*NH), 256, 0, stream>>>(qkv, vt);

    // 4. attention -> obuf bf16
    attn_mfma<<<dim3(SEQ/128, BATCH*NH), 256, 0, stream>>>(qkv, vt, obuf);

    // 5. x1 = xin + obuf @ Wo  (fp32)
    mfma_gemm<1><<<dim3(192/64, TOKENS/128), 256, 0, stream>>>(
        obuf, wot, xin, x1, nullptr, TOKENS, 192, 192);

    // 6. h2 = LN2(x1) bf16
    ln_kernel<<<TOKENS, 64, 0, stream>>>(x1, ln2_w, ln2_b, h2);

    // 7. g = gelu(h2 @ W1) bf16
    mfma_gemm<2><<<dim3(768/64, TOKENS/128), 256, 0, stream>>>(
        h2, w1t, nullptr, nullptr, gbuf, TOKENS, 768, 192);

    // 8. y = x1 + g @ W2 (fp32)
    mfma_gemm<1><<<dim3(192/64, TOKENS/128), 256, 0, stream>>>(
        gbuf, w2t, x1, ybuf, nullptr, TOKENS, 192, 768);

    // 9. out += y * h_post
    {
        const int n4 = TOKENS * (ND / 4);
        final_kernel<<<(n4 + 255) / 256, 256, 0, stream>>>(ybuf, hpost, out);
    }
}

// Round 5
// 628.374 us; speedup vs baseline: 14.3230x; 1.1101x over previous
//
#include <hip/hip_runtime.h>
#include <hip/hip_bf16.h>
#include <math.h>

// Problem constants
#define BATCH 32
#define SEQ   1024
#define NS    4
#define DIM   192
#define ND    768
#define NH    3
#define HD    64
#define MLP   768
#define TOKENS (BATCH*SEQ)   // 32768

typedef __bf16 bf16;
typedef bf16  bf16x8 __attribute__((ext_vector_type(8)));
typedef bf16  bf16x4 __attribute__((ext_vector_type(4)));
typedef float f32x4  __attribute__((ext_vector_type(4)));

#define MFMA16(a,b,c) __builtin_amdgcn_mfma_f32_16x16x32_bf16(a,b,c,0,0,0)
#define LOG2E 1.44269504088896f

__device__ inline float gelu_tanh(float x) {
    float x3 = x * x * x;
    return 0.5f * x * (1.0f + tanhf(0.7978845608028654f * (x + 0.044715f * x3)));
}

// ---------------------------------------------------------------------------
// Fused weight prep. z = 0..5: dst[N][K] = scale * src[K][N]; z = 6: phiw.
// block (32,8)
// ---------------------------------------------------------------------------
__global__ __launch_bounds__(256) void wprep_kernel(
    const float* __restrict__ Wq, const float* __restrict__ Wk,
    const float* __restrict__ Wv, const float* __restrict__ Wo,
    const float* __restrict__ W1, const float* __restrict__ W2,
    const float* __restrict__ nw, const float* __restrict__ ppre,
    const float* __restrict__ ppost, const float* __restrict__ pres,
    bf16* __restrict__ wqkv, bf16* __restrict__ wot,
    bf16* __restrict__ w1t, bf16* __restrict__ w2t, bf16* __restrict__ phiw)
{
    const int z = blockIdx.z;
    const int x = threadIdx.x, y = threadIdx.y;
    if (z == 6) {
        if (blockIdx.y != 0 || blockIdx.x >= 3) return;
        const int k = blockIdx.x * 256 + y * 32 + x;
        const float w = nw[k];
#pragma unroll
        for (int n = 0; n < 4; n++)  phiw[n * ND + k]     = (bf16)(w * ppre[k*4 + n]);
#pragma unroll
        for (int n = 0; n < 4; n++)  phiw[(4+n) * ND + k] = (bf16)(w * ppost[k*4 + n]);
#pragma unroll
        for (int n = 0; n < 16; n++) phiw[(8+n) * ND + k] = (bf16)(w * pres[k*16 + n]);
#pragma unroll
        for (int n = 24; n < 32; n++) phiw[n * ND + k]    = (bf16)0.f;
        return;
    }
    const float* src; bf16* dst; int K, N; float scale = 1.f;
    switch (z) {
        case 0: src = Wq; dst = wqkv;            K = 192; N = 192;
                scale = 0.125f * LOG2E; break;   // 1/sqrt(64) * log2(e) for exp2
        case 1: src = Wk; dst = wqkv + 192*192;  K = 192; N = 192; break;
        case 2: src = Wv; dst = wqkv + 2*192*192;K = 192; N = 192; break;
        case 3: src = Wo; dst = wot;             K = 192; N = 192; break;
        case 4: src = W1; dst = w1t;             K = 192; N = 768; break;
        default:src = W2; dst = w2t;             K = 768; N = 192; break;
    }
    const int n0 = blockIdx.x * 32, k0 = blockIdx.y * 32;
    if (n0 >= N || k0 >= K) return;
    __shared__ float t[32][33];
#pragma unroll
    for (int i = 0; i < 4; i++)
        t[y + 8*i][x] = src[(size_t)(k0 + y + 8*i) * N + n0 + x];
    __syncthreads();
#pragma unroll
    for (int i = 0; i < 4; i++)
        dst[(size_t)(n0 + y + 8*i) * K + k0 + x] = (bf16)(scale * t[x][y + 8*i]);
}

// ---------------------------------------------------------------------------
// prep: one wave per token. rinv[t] = rsqrt(mean(x^2)+eps); xb = bf16(x)
// ---------------------------------------------------------------------------
__global__ __launch_bounds__(64) void prep_kernel(
    const float* __restrict__ x, bf16* __restrict__ xb, float* __restrict__ rinv)
{
    const int tok = blockIdx.x, lane = threadIdx.x;
    const float* xt = x + (size_t)tok * ND;
    float4 xv[3];
    float ssq = 0.f;
#pragma unroll
    for (int r = 0; r < 3; r++) {
        xv[r] = ((const float4*)xt)[lane + 64 * r];
        ssq += xv[r].x*xv[r].x + xv[r].y*xv[r].y + xv[r].z*xv[r].z + xv[r].w*xv[r].w;
    }
#pragma unroll
    for (int off = 32; off; off >>= 1) ssq += __shfl_xor(ssq, off);
    if (lane == 0) rinv[tok] = rsqrtf(ssq / (float)ND + 1e-8f);
#pragma unroll
    for (int r = 0; r < 3; r++) {
        bf16x4 o = {(bf16)xv[r].x, (bf16)xv[r].y, (bf16)xv[r].z, (bf16)xv[r].w};
        *(bf16x4*)(xb + (size_t)tok * ND + 4 * (lane + 64 * r)) = o;
    }
}

// ---------------------------------------------------------------------------
// dots: MFMA GEMM  dots[t][n] = rinv[t] * (xb[t][:] . phiw[n][:])
// ---------------------------------------------------------------------------
__global__ __launch_bounds__(256) void dots_kernel(
    const bf16* __restrict__ xb, const bf16* __restrict__ phiw,
    const float* __restrict__ rinv, float* __restrict__ dots)
{
    const int tid = threadIdx.x, lane = tid & 63, w = tid >> 6;
    const int quad = lane >> 4, c = lane & 15;
    const int tok0 = blockIdx.x * 64 + w * 16;

    f32x4 acc0 = {0.f,0.f,0.f,0.f}, acc1 = {0.f,0.f,0.f,0.f};
    const bf16* arow = xb + (size_t)(tok0 + c) * ND + quad * 8;
    const bf16* b0   = phiw + (size_t)c * ND + quad * 8;
    const bf16* b1   = phiw + (size_t)(16 + c) * ND + quad * 8;
#pragma unroll 6
    for (int k0 = 0; k0 < ND; k0 += 32) {
        bf16x8 af  = *(const bf16x8*)(arow + k0);
        bf16x8 bf0 = *(const bf16x8*)(b0 + k0);
        bf16x8 bf1 = *(const bf16x8*)(b1 + k0);
        acc0 = MFMA16(af, bf0, acc0);
        acc1 = MFMA16(af, bf1, acc1);
    }
#pragma unroll
    for (int r = 0; r < 4; r++) {
        const int tok = tok0 + quad * 4 + r;
        const float s = rinv[tok];
        dots[(size_t)tok * 32 + c]      = acc0[r] * s;
        dots[(size_t)tok * 32 + 16 + c] = acc1[r] * s;
    }
}

// ---------------------------------------------------------------------------
// sink: ONE LANE PER TOKEN. sigmoid gates + 20-iter 4x4 sinkhorn, all regs.
// ---------------------------------------------------------------------------
__global__ __launch_bounds__(256) void sink_kernel(
    const float* __restrict__ dots, const float* __restrict__ b_pre,
    const float* __restrict__ b_post, const float* __restrict__ b_res,
    const float* __restrict__ a_pre, const float* __restrict__ a_post,
    const float* __restrict__ a_res,
    float* __restrict__ hgate, float* __restrict__ hpost)
{
    const int tok = blockIdx.x * 256 + threadIdx.x;
    const float* dt = dots + (size_t)tok * 32;
    float d[24];
#pragma unroll
    for (int i = 0; i < 6; i++) *(float4*)&d[i*4] = *(const float4*)(dt + i*4);

    const float apre = a_pre[0], apost = a_post[0], ares = a_res[0];
    float hpre[4], hpo[4], m[16];
#pragma unroll
    for (int i = 0; i < 4; i++) {
        hpre[i] = 1.f / (1.f + __expf(-(apre  * d[i]     + b_pre[i])));
        hpo[i]  = 2.f / (1.f + __expf(-(apost * d[4 + i] + b_post[i])));
    }
#pragma unroll
    for (int p = 0; p < 16; p++) m[p] = ares * d[8 + p] + b_res[p];

    float gm = m[0];
#pragma unroll
    for (int p = 1; p < 16; p++) gm = fmaxf(gm, m[p]);
#pragma unroll
    for (int p = 0; p < 16; p++) m[p] = __expf(m[p] - gm);

    for (int it = 0; it < 20; it++) {
#pragma unroll
        for (int i = 0; i < 4; i++) {
            const float inv = 1.f / (m[i*4+0] + m[i*4+1] + m[i*4+2] + m[i*4+3] + 1e-8f);
#pragma unroll
            for (int j = 0; j < 4; j++) m[i*4+j] *= inv;
        }
#pragma unroll
        for (int j = 0; j < 4; j++) {
            const float inv = 1.f / (m[0*4+j] + m[1*4+j] + m[2*4+j] + m[3*4+j] + 1e-8f);
#pragma unroll
            for (int i = 0; i < 4; i++) m[i*4+j] *= inv;
        }
    }

    float* hg = hgate + (size_t)tok * 20;
#pragma unroll
    for (int i = 0; i < 4; i++) *(float4*)(hg + i*4) = *(float4*)&m[i*4];
    *(float4*)(hg + 16) = *(float4*)hpre;
    *(float4*)(hpost + (size_t)tok * 4) = *(float4*)hpo;
}

// ---------------------------------------------------------------------------
// mix: one wave per token. out = hres @ x, xin = hpre . x, h1 = LN1(xin) bf16
// ---------------------------------------------------------------------------
__global__ __launch_bounds__(64) void mix_kernel(
    const bf16* __restrict__ xb, const float* __restrict__ hgate,
    const float* __restrict__ ln1_w, const float* __restrict__ ln1_b,
    float* __restrict__ out, float* __restrict__ xin, bf16* __restrict__ h1)
{
    const int tok = blockIdx.x, lane = threadIdx.x;
    __shared__ float ldsx[ND];

    const bf16* xt = xb + (size_t)tok * ND;
#pragma unroll
    for (int r = 0; r < 3; r++) {
        const bf16x4 v = *(const bf16x4*)(xt + 4 * (lane + 64 * r));
        float4 f = {(float)v[0], (float)v[1], (float)v[2], (float)v[3]};
        ((float4*)ldsx)[lane + 64 * r] = f;
    }

    const float* hg = hgate + (size_t)tok * 20;
    float hres[16], hpre[4];
#pragma unroll
    for (int p = 0; p < 16; p++) hres[p] = hg[p];
#pragma unroll
    for (int i = 0; i < 4; i++) hpre[i] = hg[16 + i];

    __syncthreads();

    float* ot = out + (size_t)tok * ND;
#pragma unroll
    for (int r = 0; r < 3; r++) {
        const int g  = lane + 64 * r;
        const int p0 = 4 * g;
        const int i  = p0 / DIM;
        const int d0 = p0 % DIM;
        float4 o;
        o.x = hres[i*4+0]*ldsx[0*DIM+d0+0] + hres[i*4+1]*ldsx[1*DIM+d0+0]
            + hres[i*4+2]*ldsx[2*DIM+d0+0] + hres[i*4+3]*ldsx[3*DIM+d0+0];
        o.y = hres[i*4+0]*ldsx[0*DIM+d0+1] + hres[i*4+1]*ldsx[1*DIM+d0+1]
            + hres[i*4+2]*ldsx[2*DIM+d0+1] + hres[i*4+3]*ldsx[3*DIM+d0+1];
        o.z = hres[i*4+0]*ldsx[0*DIM+d0+2] + hres[i*4+1]*ldsx[1*DIM+d0+2]
            + hres[i*4+2]*ldsx[2*DIM+d0+2] + hres[i*4+3]*ldsx[3*DIM+d0+2];
        o.w = hres[i*4+0]*ldsx[0*DIM+d0+3] + hres[i*4+1]*ldsx[1*DIM+d0+3]
            + hres[i*4+2]*ldsx[2*DIM+d0+3] + hres[i*4+3]*ldsx[3*DIM+d0+3];
        ((float4*)ot)[g] = o;
    }

    float xi[3];
#pragma unroll
    for (int r = 0; r < 3; r++) {
        const int d = lane + 64 * r;
        xi[r] = hpre[0]*ldsx[d] + hpre[1]*ldsx[DIM+d]
              + hpre[2]*ldsx[2*DIM+d] + hpre[3]*ldsx[3*DIM+d];
    }
    float sum = xi[0] + xi[1] + xi[2];
#pragma unroll
    for (int off = 32; off; off >>= 1) sum += __shfl_xor(sum, off);
    const float mean = sum / (float)DIM;
    float vs = (xi[0]-mean)*(xi[0]-mean) + (xi[1]-mean)*(xi[1]-mean) + (xi[2]-mean)*(xi[2]-mean);
#pragma unroll
    for (int off = 32; off; off >>= 1) vs += __shfl_xor(vs, off);
    const float inv = rsqrtf(vs / (float)DIM + 1e-5f);

    float* xint = xin + (size_t)tok * DIM;
    bf16*  ht   = h1  + (size_t)tok * DIM;
#pragma unroll
    for (int r = 0; r < 3; r++) {
        const int d = lane + 64 * r;
        xint[d] = xi[r];
        ht[d]   = (bf16)((xi[r] - mean) * inv * ln1_w[d] + ln1_b[d]);
    }
}

// ---------------------------------------------------------------------------
// Barrier-free bf16 GEMM, direct global frag loads.
// Block 256 = 4 indep waves; wave tile 64 tokens x 64 n (mt=4, nt=4).
// EPI: 0 = bf16 out, 2 = gelu bf16 out
// ---------------------------------------------------------------------------
template<int EPI, int K>
__global__ __launch_bounds__(256) void gemm_bf(
    const bf16* __restrict__ A, const bf16* __restrict__ Bt,
    bf16* __restrict__ Cb, int N)
{
    const int tid = threadIdx.x, lane = tid & 63, w = tid >> 6;
    const int quad = lane >> 4, c = lane & 15;
    const int tok0 = blockIdx.y * 256 + w * 64;
    const int n0   = blockIdx.x * 64;

    f32x4 acc[4][4];
#pragma unroll
    for (int i = 0; i < 4; i++)
#pragma unroll
        for (int j = 0; j < 4; j++) acc[i][j] = (f32x4){0.f,0.f,0.f,0.f};

    const bf16* abase = A + (size_t)(tok0 + c) * K + quad * 8;
    const bf16* bbase = Bt + (size_t)(n0 + c) * K + quad * 8;
#pragma unroll 2
    for (int k0 = 0; k0 < K; k0 += 32) {
        bf16x8 af[4], bfr[4];
#pragma unroll
        for (int mt = 0; mt < 4; mt++)
            af[mt] = *(const bf16x8*)(abase + (size_t)mt * 16 * K + k0);
#pragma unroll
        for (int nt = 0; nt < 4; nt++)
            bfr[nt] = *(const bf16x8*)(bbase + (size_t)nt * 16 * K + k0);
#pragma unroll
        for (int mt = 0; mt < 4; mt++)
#pragma unroll
            for (int nt = 0; nt < 4; nt++)
                acc[mt][nt] = MFMA16(af[mt], bfr[nt], acc[mt][nt]);
    }

#pragma unroll
    for (int mt = 0; mt < 4; mt++)
#pragma unroll
        for (int r = 0; r < 4; r++) {
            const int row = tok0 + mt*16 + quad*4 + r;
#pragma unroll
            for (int nt = 0; nt < 4; nt++) {
                float v = acc[mt][nt][r];
                if (EPI == 2) v = gelu_tanh(v);
                Cb[(size_t)row * N + n0 + nt*16 + c] = (bf16)v;
            }
        }
}

// ---------------------------------------------------------------------------
// Wo GEMM + residual + LN2 fused. Wave = 16 tokens x 192 cols (nt=12).
// x1 = xin + obuf@Wo (fp32);  h2 = LN2(x1) (bf16)
// ---------------------------------------------------------------------------
__global__ __launch_bounds__(256) void gemm_wo_ln(
    const bf16* __restrict__ A, const bf16* __restrict__ Bt,
    const float* __restrict__ xin, const float* __restrict__ lw,
    const float* __restrict__ lb, float* __restrict__ x1, bf16* __restrict__ h2)
{
    const int tid = threadIdx.x, lane = tid & 63, w = tid >> 6;
    const int quad = lane >> 4, c = lane & 15;
    const int tok0 = blockIdx.x * 64 + w * 16;

    f32x4 acc[12];
#pragma unroll
    for (int j = 0; j < 12; j++) acc[j] = (f32x4){0.f,0.f,0.f,0.f};

    const bf16* abase = A + (size_t)(tok0 + c) * 192 + quad * 8;
    const bf16* bbase = Bt + (size_t)c * 192 + quad * 8;
#pragma unroll 2
    for (int k0 = 0; k0 < 192; k0 += 32) {
        bf16x8 af = *(const bf16x8*)(abase + k0);
#pragma unroll
        for (int nt = 0; nt < 12; nt++) {
            bf16x8 bfr = *(const bf16x8*)(bbase + (size_t)nt * 16 * 192 + k0);
            acc[nt] = MFMA16(af, bfr, acc[nt]);
        }
    }

#pragma unroll
    for (int r = 0; r < 4; r++) {
        const int row = tok0 + quad*4 + r;
        float v[12], s = 0.f;
#pragma unroll
        for (int nt = 0; nt < 12; nt++) {
            v[nt] = acc[nt][r] + xin[(size_t)row * 192 + nt*16 + c];
            s += v[nt];
        }
#pragma unroll
        for (int off = 1; off < 16; off <<= 1) s += __shfl_xor(s, off);
        const float mean = s / 192.f;
        float vv = 0.f;
#pragma unroll
        for (int nt = 0; nt < 12; nt++) {
            const float d = v[nt] - mean;
            vv += d * d;
        }
#pragma unroll
        for (int off = 1; off < 16; off <<= 1) vv += __shfl_xor(vv, off);
        const float inv = rsqrtf(vv / 192.f + 1e-5f);
#pragma unroll
        for (int nt = 0; nt < 12; nt++) {
            const int col = nt*16 + c;
            x1[(size_t)row * 192 + col] = v[nt];
            h2[(size_t)row * 192 + col] = (bf16)((v[nt] - mean) * inv * lw[col] + lb[col]);
        }
    }
}

// ---------------------------------------------------------------------------
// W2 GEMM + residual + h_post scale + out accumulate. Wave = 16 tok x 192.
// y = x1 + g@W2;  out[tok][i][:] += y * hpost[tok][i]
// ---------------------------------------------------------------------------
__global__ __launch_bounds__(256) void gemm_w2_final(
    const bf16* __restrict__ A, const bf16* __restrict__ Bt,
    const float* __restrict__ x1, const float* __restrict__ hpost,
    float* __restrict__ out)
{
    const int tid = threadIdx.x, lane = tid & 63, w = tid >> 6;
    const int quad = lane >> 4, c = lane & 15;
    const int tok0 = blockIdx.x * 64 + w * 16;

    f32x4 acc[12];
#pragma unroll
    for (int j = 0; j < 12; j++) acc[j] = (f32x4){0.f,0.f,0.f,0.f};

    const bf16* abase = A + (size_t)(tok0 + c) * 768 + quad * 8;
    const bf16* bbase = Bt + (size_t)c * 768 + quad * 8;
#pragma unroll 2
    for (int k0 = 0; k0 < 768; k0 += 32) {
        bf16x8 af = *(const bf16x8*)(abase + k0);
#pragma unroll
        for (int nt = 0; nt < 12; nt++) {
            bf16x8 bfr = *(const bf16x8*)(bbase + (size_t)nt * 16 * 768 + k0);
            acc[nt] = MFMA16(af, bfr, acc[nt]);
        }
    }

#pragma unroll
    for (int r = 0; r < 4; r++) {
        const int row = tok0 + quad*4 + r;
        const float4 hp = *(const float4*)(hpost + (size_t)row * 4);
        float y[12];
#pragma unroll
        for (int nt = 0; nt < 12; nt++)
            y[nt] = acc[nt][r] + x1[(size_t)row * 192 + nt*16 + c];
        float* orow = out + (size_t)row * ND;
#pragma unroll
        for (int i = 0; i < 4; i++) {
            const float h = (i == 0) ? hp.x : (i == 1) ? hp.y : (i == 2) ? hp.z : hp.w;
#pragma unroll
            for (int nt = 0; nt < 12; nt++) {
                const int col = i * 192 + nt*16 + c;
                orow[col] += y[nt] * h;
            }
        }
    }
}

// ---------------------------------------------------------------------------
// V transpose: qkv[tok][384+h*64+d] -> vt[bh][d][seq]  (bf16)
// ---------------------------------------------------------------------------
__global__ __launch_bounds__(256) void vtrans_kernel(
    const bf16* __restrict__ qkv, bf16* __restrict__ vt)
{
    __shared__ bf16 t[64][72];
    const int tid = threadIdx.x;
    const int bh = blockIdx.y, b = bh / NH, h = bh % NH;
    const int s0 = blockIdx.x * 64;

#pragma unroll
    for (int i = 0; i < 2; i++) {
        const int chunk = tid + 256 * i;
        const int srow = chunk >> 3, g = chunk & 7;
        *(uint4*)&t[srow][g * 8] =
            *(const uint4*)(qkv + (size_t)(b * SEQ + s0 + srow) * 576 + 384 + h * 64 + g * 8);
    }
    __syncthreads();
#pragma unroll
    for (int i = 0; i < 2; i++) {
        const int chunk = tid + 256 * i;
        const int d = chunk >> 3, sg = chunk & 7;
        bf16x8 v;
#pragma unroll
        for (int j = 0; j < 8; j++) v[j] = t[sg * 8 + j][d];
        *(bf16x8*)(vt + ((size_t)bh * HD + d) * SEQ + s0 + sg * 8) = v;
    }
}

// ---------------------------------------------------------------------------
// MFMA flash attention: ONE WAVE per block (32 queries), grid (32, 96).
// exp2-based softmax (log2e/8 folded into Wq), lsum deferred to epilogue.
// ---------------------------------------------------------------------------
__global__ __launch_bounds__(64) void attn_mfma(
    const bf16* __restrict__ qkv, const bf16* __restrict__ vt,
    bf16* __restrict__ obuf)
{
    __shared__ bf16 Pw[32 * 64];
    const int lane = threadIdx.x;
    const int quad = lane >> 4, c = lane & 15;
    const int bh = blockIdx.y, b = bh / NH, h = bh % NH;
    const int q0 = blockIdx.x * 32;

    const bf16* kbase = qkv + (size_t)b * SEQ * 576 + 192 + h * 64;
    const bf16* vbase = vt + (size_t)bh * HD * SEQ;

    bf16x8 qf[2][2];
#pragma unroll
    for (int mt = 0; mt < 2; mt++)
#pragma unroll
        for (int ch = 0; ch < 2; ch++)
            qf[mt][ch] = *(const bf16x8*)(qkv + (size_t)(b * SEQ + q0 + mt*16 + c) * 576
                                              + h * 64 + ch * 32 + quad * 8);

    f32x4 of[2][4];
    float lst[2][4];
#pragma unroll
    for (int mt = 0; mt < 2; mt++)
#pragma unroll
        for (int r = 0; r < 4; r++) lst[mt][r] = 0.f;
#pragma unroll
    for (int mt = 0; mt < 2; mt++)
#pragma unroll
        for (int dt = 0; dt < 4; dt++) of[mt][dt] = (f32x4){0.f, 0.f, 0.f, 0.f};

#pragma unroll 1
    for (int kt = 0; kt < SEQ / 64; kt++) {
        f32x4 sf[2][4];
#pragma unroll
        for (int mt = 0; mt < 2; mt++)
#pragma unroll
            for (int nt = 0; nt < 4; nt++) sf[mt][nt] = (f32x4){0.f, 0.f, 0.f, 0.f};
#pragma unroll
        for (int ch = 0; ch < 2; ch++) {
            bf16x8 kf[4];
#pragma unroll
            for (int nt = 0; nt < 4; nt++)
                kf[nt] = *(const bf16x8*)(kbase + (size_t)(kt*64 + nt*16 + c) * 576
                                               + ch * 32 + quad * 8);
#pragma unroll
            for (int mt = 0; mt < 2; mt++)
#pragma unroll
                for (int nt = 0; nt < 4; nt++)
                    sf[mt][nt] = MFMA16(qf[mt][ch], kf[nt], sf[mt][nt]);
        }

        // exp2 + per-lane partial row-sum (exact: no max shift, no rescale)
#pragma unroll
        for (int mt = 0; mt < 2; mt++)
#pragma unroll
            for (int r = 0; r < 4; r++) {
                float rs = 0.f;
#pragma unroll
                for (int nt = 0; nt < 4; nt++) {
                    const float p = exp2f(sf[mt][nt][r]);
                    sf[mt][nt][r] = p;
                    rs += p;
                }
                lst[mt][r] += rs;
            }

        // P -> LDS (bf16, row-swizzled)
#pragma unroll
        for (int mt = 0; mt < 2; mt++)
#pragma unroll
            for (int nt = 0; nt < 4; nt++)
#pragma unroll
                for (int r = 0; r < 4; r++) {
                    const int row = mt*16 + quad*4 + r;
                    const int col = nt*16 + c;
                    Pw[row*64 + (((col >> 3) ^ (row & 7)) * 8) + (col & 7)] =
                        (bf16)sf[mt][nt][r];
                }

        // O += P V
#pragma unroll
        for (int ch = 0; ch < 2; ch++) {
            bf16x8 vf[4], pf[2];
#pragma unroll
            for (int dt = 0; dt < 4; dt++)
                vf[dt] = *(const bf16x8*)(vbase + (size_t)(dt*16 + c) * SEQ
                                               + kt*64 + ch*32 + quad*8);
#pragma unroll
            for (int mt = 0; mt < 2; mt++) {
                const int row = mt*16 + c;
                pf[mt] = *(const bf16x8*)(Pw + row*64 + (((ch*4 + quad) ^ (c & 7)) * 8));
            }
#pragma unroll
            for (int mt = 0; mt < 2; mt++)
#pragma unroll
                for (int dt = 0; dt < 4; dt++)
                    of[mt][dt] = MFMA16(pf[mt], vf[dt], of[mt][dt]);
        }
    }

    // epilogue: one 16-lane reduction of the deferred row-sums, then store
#pragma unroll
    for (int mt = 0; mt < 2; mt++)
#pragma unroll
        for (int r = 0; r < 4; r++) {
            float s = lst[mt][r];
#pragma unroll
            for (int off = 1; off < 16; off <<= 1) s += __shfl_xor(s, off);
            const float inv = 1.0f / s;
            const size_t tok = (size_t)b * SEQ + q0 + mt*16 + quad*4 + r;
#pragma unroll
            for (int dt = 0; dt < 4; dt++)
                obuf[tok * DIM + h*64 + dt*16 + c] = (bf16)(of[mt][dt][r] * inv);
        }
}

// ---------------------------------------------------------------------------
extern "C" void kernel_launch(void* const* d_in, const int* in_sizes, int n_in,
                              void* d_out, int out_size, void* d_ws, size_t ws_size,
                              hipStream_t stream) {
    const float* x         = (const float*)d_in[0];
    const float* norm_w    = (const float*)d_in[1];
    const float* phi_pre   = (const float*)d_in[2];
    const float* phi_post  = (const float*)d_in[3];
    const float* phi_res   = (const float*)d_in[4];
    const float* b_pre     = (const float*)d_in[5];
    const float* b_post    = (const float*)d_in[6];
    const float* b_res     = (const float*)d_in[7];
    const float* alpha_pre = (const float*)d_in[8];
    const float* alpha_post= (const float*)d_in[9];
    const float* alpha_res = (const float*)d_in[10];
    const float* ln1_w     = (const float*)d_in[11];
    const float* ln1_b     = (const float*)d_in[12];
    const float* Wq        = (const float*)d_in[13];
    const float* Wk        = (const float*)d_in[14];
    const float* Wv        = (const float*)d_in[15];
    const float* Wo        = (const float*)d_in[16];
    const float* ln2_w     = (const float*)d_in[17];
    const float* ln2_b     = (const float*)d_in[18];
    const float* W1        = (const float*)d_in[19];
    const float* W2        = (const float*)d_in[20];

    float* out = (float*)d_out;
    float* ws  = (float*)d_ws;

    // ---- workspace carve (float units; every base 16B-aligned) ----
    const size_t TBf = (size_t)TOKENS * DIM;        // 6,291,456
    float* xin   = ws;                               // fp32 [TBf]
    float* x1    = ws + TBf;                         // fp32 [TBf]
    float* hpost = ws + 2 * TBf;                     // fp32 [131072]
    float* rinv  = hpost + 131072;                   // fp32 [32768]
    bf16*  phiw  = (bf16*)(rinv + 32768);            // [32][768]
    bf16*  wqkv  = phiw + 32 * ND;                   // [576][192]
    bf16*  wot   = wqkv + 576 * 192;                 // [192][192]
    bf16*  w1t   = wot + 192 * 192;                  // [768][192]
    bf16*  w2t   = w1t + 768 * 192;                  // [192][768]
    float* regAC = (float*)(w2t + 192 * 768);
    bf16*  xb    = (bf16*)regAC;                     // [32768][768] (dead after mix)
    bf16*  qkv   = (bf16*)regAC;                     // [32768][576]
    bf16*  vt    = qkv + (size_t)TOKENS * 576;       // [96][64][1024]
    bf16*  gbuf  = (bf16*)regAC;                     // [32768][768]
    float* regBD = regAC + 12582912;
    bf16*  h1    = (bf16*)regBD;                     // [32768][192]
    bf16*  obuf  = h1;                               // alias (h1 dead after QKV)
    bf16*  h2    = h1 + TBf;                         // [32768][192]
    float* dotsb = regBD + TBf / 2;                  // fp32 [32768][32] (h2 slot, dead before wo_ln)
    float* hgate = dotsb + (size_t)TOKENS * 32;      // fp32 [32768][20]

    // 0. weight prep (single fused launch)
    wprep_kernel<<<dim3(24, 24, 7), dim3(32, 8), 0, stream>>>(
        Wq, Wk, Wv, Wo, W1, W2, norm_w, phi_pre, phi_post, phi_res,
        wqkv, wot, w1t, w2t, phiw);

    // 1. gating pipeline
    prep_kernel<<<TOKENS, 64, 0, stream>>>(x, xb, rinv);
    dots_kernel<<<TOKENS / 64, 256, 0, stream>>>(xb, phiw, rinv, dotsb);
    sink_kernel<<<TOKENS / 256, 256, 0, stream>>>(
        dotsb, b_pre, b_post, b_res, alpha_pre, alpha_post, alpha_res, hgate, hpost);
    mix_kernel<<<TOKENS, 64, 0, stream>>>(xb, hgate, ln1_w, ln1_b, out, xin, h1);

    // 2. fused QKV projection (barrier-free)
    gemm_bf<0, 192><<<dim3(576/64, TOKENS/256), 256, 0, stream>>>(h1, wqkv, qkv, 576);

    // 3. V transpose
    vtrans_kernel<<<dim3(SEQ/64, BATCH*NH), 256, 0, stream>>>(qkv, vt);

    // 4. attention -> obuf bf16 (1-wave blocks)
    attn_mfma<<<dim3(SEQ/32, BATCH*NH), 64, 0, stream>>>(qkv, vt, obuf);

    // 5. x1 = xin + obuf @ Wo, h2 = LN2(x1)  (fused)
    gemm_wo_ln<<<TOKENS/64, 256, 0, stream>>>(obuf, wot, xin, ln2_w, ln2_b, x1, h2);

    // 6. g = gelu(h2 @ W1) bf16 (barrier-free)
    gemm_bf<2, 192><<<dim3(768/64, TOKENS/256), 256, 0, stream>>>(h2, w1t, gbuf, 768);

    // 7. out += (x1 + g @ W2) * h_post  (fused)
    gemm_w2_final<<<TOKENS/64, 256, 0, stream>>>(gbuf, w2t, x1, hpost, out);
}

// Round 6
// 550.453 us; speedup vs baseline: 16.3505x; 1.1416x over previous
//
#include <hip/hip_runtime.h>
#include <hip/hip_bf16.h>
#include <math.h>

// Problem constants
#define BATCH 32
#define SEQ   1024
#define NS    4
#define DIM   192
#define ND    768
#define NH    3
#define HD    64
#define MLP   768
#define TOKENS (BATCH*SEQ)   // 32768

typedef __bf16 bf16;
typedef bf16  bf16x8 __attribute__((ext_vector_type(8)));
typedef bf16  bf16x4 __attribute__((ext_vector_type(4)));
typedef float f32x4  __attribute__((ext_vector_type(4)));

#define MFMA16(a,b,c) __builtin_amdgcn_mfma_f32_16x16x32_bf16(a,b,c,0,0,0)
#define LOG2E 1.44269504088896f

__device__ inline float gelu_tanh(float x) {
    float x3 = x * x * x;
    return 0.5f * x * (1.0f + tanhf(0.7978845608028654f * (x + 0.044715f * x3)));
}

// ---------------------------------------------------------------------------
// Weight prep -> FRAGMENT-LINEAR layout.
// For Bt[N][K]: element (n,k) -> ((ntile*KC + kch)*64 + quad*16 + nc)*8 + e
//   ntile=n/16, nc=n%16, kch=k/32, quad=(k%32)/8, e=k%8, KC=K/32.
// A wave's B-frag load is then `base + lane*8` = contiguous 1KB.
// z = 0..5: the six weights; z = 6: phiw (norm_w-scaled phi, 32xND).
// ---------------------------------------------------------------------------
__global__ __launch_bounds__(256) void wprep_kernel(
    const float* __restrict__ Wq, const float* __restrict__ Wk,
    const float* __restrict__ Wv, const float* __restrict__ Wo,
    const float* __restrict__ W1, const float* __restrict__ W2,
    const float* __restrict__ nw, const float* __restrict__ ppre,
    const float* __restrict__ ppost, const float* __restrict__ pres,
    bf16* __restrict__ wqkv, bf16* __restrict__ wot,
    bf16* __restrict__ w1t, bf16* __restrict__ w2t, bf16* __restrict__ phiw)
{
    const int z = blockIdx.z;
    const int tid = blockIdx.x * 256 + threadIdx.x;
    if (z == 6) {
        if (tid >= 32 * 96) return;          // N=32, K=768, KC=24
        const int n = tid / 96, k8 = tid % 96;
        const int kch = k8 >> 2, quad = k8 & 3;
        const int ntile = n >> 4, nc = n & 15;
        bf16* d = phiw + ((size_t)(ntile * 24 + kch) * 64 + quad * 16 + nc) * 8;
#pragma unroll
        for (int e = 0; e < 8; e++) {
            const int k = k8 * 8 + e;
            float v;
            if      (n < 4)  v = ppre [k * 4  + n];
            else if (n < 8)  v = ppost[k * 4  + n - 4];
            else if (n < 24) v = pres [k * 16 + n - 8];
            else             v = 0.f;
            d[e] = (bf16)(nw[k] * v);
        }
        return;
    }
    const float* src; bf16* dst; int K, N; float scale = 1.f;
    switch (z) {
        case 0: src = Wq; dst = wqkv;            K = 192; N = 192;
                scale = 0.125f * LOG2E; break;   // 1/sqrt(64)*log2e (exp2 softmax)
        case 1: src = Wk; dst = wqkv + 36864;    K = 192; N = 192; break;
        case 2: src = Wv; dst = wqkv + 73728;    K = 192; N = 192; break;
        case 3: src = Wo; dst = wot;             K = 192; N = 192; break;
        case 4: src = W1; dst = w1t;             K = 192; N = 768; break;
        default:src = W2; dst = w2t;             K = 768; N = 192; break;
    }
    const int K8 = K >> 3, KC = K >> 5;
    if (tid >= N * K8) return;
    const int n = tid / K8, k8 = tid % K8;
    const int kch = k8 >> 2, quad = k8 & 3;
    const int ntile = n >> 4, nc = n & 15;
    bf16* d = dst + ((size_t)(ntile * KC + kch) * 64 + quad * 16 + nc) * 8;
#pragma unroll
    for (int e = 0; e < 8; e++)
        d[e] = (bf16)(scale * src[(size_t)(k8 * 8 + e) * N + n]);
}

// ---------------------------------------------------------------------------
// prep: one wave per token. rinv[t] = rsqrt(mean(x^2)+eps); xb = bf16(x)
// ---------------------------------------------------------------------------
__global__ __launch_bounds__(64) void prep_kernel(
    const float* __restrict__ x, bf16* __restrict__ xb, float* __restrict__ rinv)
{
    const int tok = blockIdx.x, lane = threadIdx.x;
    const float* xt = x + (size_t)tok * ND;
    float4 xv[3];
    float ssq = 0.f;
#pragma unroll
    for (int r = 0; r < 3; r++) {
        xv[r] = ((const float4*)xt)[lane + 64 * r];
        ssq += xv[r].x*xv[r].x + xv[r].y*xv[r].y + xv[r].z*xv[r].z + xv[r].w*xv[r].w;
    }
#pragma unroll
    for (int off = 32; off; off >>= 1) ssq += __shfl_xor(ssq, off);
    if (lane == 0) rinv[tok] = rsqrtf(ssq / (float)ND + 1e-8f);
#pragma unroll
    for (int r = 0; r < 3; r++) {
        bf16x4 o = {(bf16)xv[r].x, (bf16)xv[r].y, (bf16)xv[r].z, (bf16)xv[r].w};
        *(bf16x4*)(xb + (size_t)tok * ND + 4 * (lane + 64 * r)) = o;
    }
}

// ---------------------------------------------------------------------------
// dots: MFMA GEMM  dots[t][n] = rinv[t] * (xb[t][:] . phi'[n][:])
// phiw frag-linear (KC=24, 2 n-tiles).
// ---------------------------------------------------------------------------
__global__ __launch_bounds__(256) void dots_kernel(
    const bf16* __restrict__ xb, const bf16* __restrict__ phiw,
    const float* __restrict__ rinv, float* __restrict__ dots)
{
    const int tid = threadIdx.x, lane = tid & 63, w = tid >> 6;
    const int quad = lane >> 4, c = lane & 15;
    const int tok0 = blockIdx.x * 64 + w * 16;

    f32x4 acc0 = {0.f,0.f,0.f,0.f}, acc1 = {0.f,0.f,0.f,0.f};
    const bf16* arow = xb + (size_t)(tok0 + c) * ND + quad * 8;
    const bf16* bbase = phiw + lane * 8;
#pragma unroll 6
    for (int k0 = 0; k0 < ND; k0 += 32) {
        const int kch = k0 >> 5;
        bf16x8 af  = *(const bf16x8*)(arow + k0);
        bf16x8 bf0 = *(const bf16x8*)(bbase + (size_t)kch * 512);
        bf16x8 bf1 = *(const bf16x8*)(bbase + (size_t)(24 + kch) * 512);
        acc0 = MFMA16(af, bf0, acc0);
        acc1 = MFMA16(af, bf1, acc1);
    }
#pragma unroll
    for (int r = 0; r < 4; r++) {
        const int tok = tok0 + quad * 4 + r;
        const float s = rinv[tok];
        dots[(size_t)tok * 32 + c]      = acc0[r] * s;
        dots[(size_t)tok * 32 + 16 + c] = acc1[r] * s;
    }
}

// ---------------------------------------------------------------------------
// sink: ONE LANE PER TOKEN. sigmoid gates + 20-iter 4x4 sinkhorn, all regs.
// hgate[t][20] = {hres[16], hpre[4]}; hpost[t][4].
// ---------------------------------------------------------------------------
__global__ __launch_bounds__(256) void sink_kernel(
    const float* __restrict__ dots, const float* __restrict__ b_pre,
    const float* __restrict__ b_post, const float* __restrict__ b_res,
    const float* __restrict__ a_pre, const float* __restrict__ a_post,
    const float* __restrict__ a_res,
    float* __restrict__ hgate, float* __restrict__ hpost)
{
    const int tok = blockIdx.x * 256 + threadIdx.x;
    const float* dt = dots + (size_t)tok * 32;
    float d[24];
#pragma unroll
    for (int i = 0; i < 6; i++) *(float4*)&d[i*4] = *(const float4*)(dt + i*4);

    const float apre = a_pre[0], apost = a_post[0], ares = a_res[0];
    float hpre[4], hpo[4], m[16];
#pragma unroll
    for (int i = 0; i < 4; i++) {
        hpre[i] = 1.f / (1.f + __expf(-(apre  * d[i]     + b_pre[i])));
        hpo[i]  = 2.f / (1.f + __expf(-(apost * d[4 + i] + b_post[i])));
    }
#pragma unroll
    for (int p = 0; p < 16; p++) m[p] = ares * d[8 + p] + b_res[p];

    float gm = m[0];
#pragma unroll
    for (int p = 1; p < 16; p++) gm = fmaxf(gm, m[p]);
#pragma unroll
    for (int p = 0; p < 16; p++) m[p] = __expf(m[p] - gm);

    for (int it = 0; it < 20; it++) {
#pragma unroll
        for (int i = 0; i < 4; i++) {
            const float inv = 1.f / (m[i*4+0] + m[i*4+1] + m[i*4+2] + m[i*4+3] + 1e-8f);
#pragma unroll
            for (int j = 0; j < 4; j++) m[i*4+j] *= inv;
        }
#pragma unroll
        for (int j = 0; j < 4; j++) {
            const float inv = 1.f / (m[0*4+j] + m[1*4+j] + m[2*4+j] + m[3*4+j] + 1e-8f);
#pragma unroll
            for (int i = 0; i < 4; i++) m[i*4+j] *= inv;
        }
    }

    float* hg = hgate + (size_t)tok * 20;
#pragma unroll
    for (int i = 0; i < 4; i++) *(float4*)(hg + i*4) = *(float4*)&m[i*4];
    *(float4*)(hg + 16) = *(float4*)hpre;
    *(float4*)(hpost + (size_t)tok * 4) = *(float4*)hpo;
}

// ---------------------------------------------------------------------------
// mix: one wave per token. xin = hpre . x streams; h1 = LN1(xin) bf16.
// (x_res is now produced by gemm_w2_final's epilogue.)
// ---------------------------------------------------------------------------
__global__ __launch_bounds__(64) void mix_kernel(
    const bf16* __restrict__ xb, const float* __restrict__ hgate,
    const float* __restrict__ ln1_w, const float* __restrict__ ln1_b,
    float* __restrict__ xin, bf16* __restrict__ h1)
{
    const int tok = blockIdx.x, lane = threadIdx.x;
    __shared__ float ldsx[ND];

    const bf16* xt = xb + (size_t)tok * ND;
#pragma unroll
    for (int r = 0; r < 3; r++) {
        const bf16x4 v = *(const bf16x4*)(xt + 4 * (lane + 64 * r));
        float4 f = {(float)v[0], (float)v[1], (float)v[2], (float)v[3]};
        ((float4*)ldsx)[lane + 64 * r] = f;
    }

    const float* hg = hgate + (size_t)tok * 20 + 16;
    float hpre[4];
#pragma unroll
    for (int i = 0; i < 4; i++) hpre[i] = hg[i];

    __syncthreads();

    float xi[3];
#pragma unroll
    for (int r = 0; r < 3; r++) {
        const int d = lane + 64 * r;
        xi[r] = hpre[0]*ldsx[d] + hpre[1]*ldsx[DIM+d]
              + hpre[2]*ldsx[2*DIM+d] + hpre[3]*ldsx[3*DIM+d];
    }
    float sum = xi[0] + xi[1] + xi[2];
#pragma unroll
    for (int off = 32; off; off >>= 1) sum += __shfl_xor(sum, off);
    const float mean = sum / (float)DIM;
    float vs = (xi[0]-mean)*(xi[0]-mean) + (xi[1]-mean)*(xi[1]-mean) + (xi[2]-mean)*(xi[2]-mean);
#pragma unroll
    for (int off = 32; off; off >>= 1) vs += __shfl_xor(vs, off);
    const float inv = rsqrtf(vs / (float)DIM + 1e-5f);

    float* xint = xin + (size_t)tok * DIM;
    bf16*  ht   = h1  + (size_t)tok * DIM;
#pragma unroll
    for (int r = 0; r < 3; r++) {
        const int d = lane + 64 * r;
        xint[d] = xi[r];
        ht[d]   = (bf16)((xi[r] - mean) * inv * ln1_w[d] + ln1_b[d]);
    }
}

// ---------------------------------------------------------------------------
// Barrier-free bf16 GEMM, frag-linear B. Wave tile 64 tok x 64 n.
// EPI: 0 = bf16 out, 2 = gelu bf16 out
// ---------------------------------------------------------------------------
template<int EPI, int K>
__global__ __launch_bounds__(256) void gemm_bf(
    const bf16* __restrict__ A, const bf16* __restrict__ Bt,
    bf16* __restrict__ Cb, int N)
{
    const int tid = threadIdx.x, lane = tid & 63, w = tid >> 6;
    const int quad = lane >> 4, c = lane & 15;
    const int tok0 = blockIdx.y * 256 + w * 64;
    const int n0   = blockIdx.x * 64;
    const int KC   = K >> 5;

    f32x4 acc[4][4];
#pragma unroll
    for (int i = 0; i < 4; i++)
#pragma unroll
        for (int j = 0; j < 4; j++) acc[i][j] = (f32x4){0.f,0.f,0.f,0.f};

    const bf16* abase = A + (size_t)(tok0 + c) * K + quad * 8;
    const bf16* bbase = Bt + (size_t)(n0 >> 4) * KC * 512 + lane * 8;
#pragma unroll 2
    for (int k0 = 0; k0 < K; k0 += 32) {
        const int kch = k0 >> 5;
        bf16x8 af[4], bfr[4];
#pragma unroll
        for (int mt = 0; mt < 4; mt++)
            af[mt] = *(const bf16x8*)(abase + (size_t)mt * 16 * K + k0);
#pragma unroll
        for (int nt = 0; nt < 4; nt++)
            bfr[nt] = *(const bf16x8*)(bbase + (size_t)(nt * KC + kch) * 512);
#pragma unroll
        for (int mt = 0; mt < 4; mt++)
#pragma unroll
            for (int nt = 0; nt < 4; nt++)
                acc[mt][nt] = MFMA16(af[mt], bfr[nt], acc[mt][nt]);
    }

#pragma unroll
    for (int mt = 0; mt < 4; mt++)
#pragma unroll
        for (int r = 0; r < 4; r++) {
            const int row = tok0 + mt*16 + quad*4 + r;
#pragma unroll
            for (int nt = 0; nt < 4; nt++) {
                float v = acc[mt][nt][r];
                if (EPI == 2) v = gelu_tanh(v);
                Cb[(size_t)row * N + n0 + nt*16 + c] = (bf16)v;
            }
        }
}

// ---------------------------------------------------------------------------
// Wo GEMM + residual + LN2 fused. Wave = 16 tokens x 192 cols (nt=12).
// x1 = xin + obuf@Wo (fp32);  h2 = LN2(x1) (bf16). Frag-linear B, KC=6.
// ---------------------------------------------------------------------------
__global__ __launch_bounds__(256) void gemm_wo_ln(
    const bf16* __restrict__ A, const bf16* __restrict__ Bt,
    const float* __restrict__ xin, const float* __restrict__ lw,
    const float* __restrict__ lb, float* __restrict__ x1, bf16* __restrict__ h2)
{
    const int tid = threadIdx.x, lane = tid & 63, w = tid >> 6;
    const int quad = lane >> 4, c = lane & 15;
    const int tok0 = blockIdx.x * 64 + w * 16;

    f32x4 acc[12];
#pragma unroll
    for (int j = 0; j < 12; j++) acc[j] = (f32x4){0.f,0.f,0.f,0.f};

    const bf16* abase = A + (size_t)(tok0 + c) * 192 + quad * 8;
    const bf16* bbase = Bt + lane * 8;
#pragma unroll 2
    for (int k0 = 0; k0 < 192; k0 += 32) {
        const int kch = k0 >> 5;
        bf16x8 af = *(const bf16x8*)(abase + k0);
#pragma unroll
        for (int nt = 0; nt < 12; nt++) {
            bf16x8 bfr = *(const bf16x8*)(bbase + (size_t)(nt * 6 + kch) * 512);
            acc[nt] = MFMA16(af, bfr, acc[nt]);
        }
    }

#pragma unroll
    for (int r = 0; r < 4; r++) {
        const int row = tok0 + quad*4 + r;
        float v[12], s = 0.f;
#pragma unroll
        for (int nt = 0; nt < 12; nt++) {
            v[nt] = acc[nt][r] + xin[(size_t)row * 192 + nt*16 + c];
            s += v[nt];
        }
#pragma unroll
        for (int off = 1; off < 16; off <<= 1) s += __shfl_xor(s, off);
        const float mean = s / 192.f;
        float vv = 0.f;
#pragma unroll
        for (int nt = 0; nt < 12; nt++) {
            const float d = v[nt] - mean;
            vv += d * d;
        }
#pragma unroll
        for (int off = 1; off < 16; off <<= 1) vv += __shfl_xor(vv, off);
        const float inv = rsqrtf(vv / 192.f + 1e-5f);
#pragma unroll
        for (int nt = 0; nt < 12; nt++) {
            const int col = nt*16 + c;
            x1[(size_t)row * 192 + col] = v[nt];
            h2[(size_t)row * 192 + col] = (bf16)((v[nt] - mean) * inv * lw[col] + lb[col]);
        }
    }
}

// ---------------------------------------------------------------------------
// W2 GEMM + residual + h_post scale + x_res, fully fused; out is WRITE-ONLY.
// Grid (TOKENS/64, 3): blockIdx.y = 64-col slice. Wave = 16 tok x 64 cols.
// out[t][i][col] = sum_j hres[i][j]*x[t][j][col] + (x1+g@W2)[t][col]*hpost[t][i]
// ---------------------------------------------------------------------------
__global__ __launch_bounds__(256) void gemm_w2_final(
    const bf16* __restrict__ A, const bf16* __restrict__ Bt,
    const float* __restrict__ x1, const float* __restrict__ x,
    const float* __restrict__ hgate, const float* __restrict__ hpost,
    float* __restrict__ out)
{
    const int tid = threadIdx.x, lane = tid & 63, w = tid >> 6;
    const int quad = lane >> 4, c = lane & 15;
    const int tok0 = blockIdx.x * 64 + w * 16;
    const int s = blockIdx.y;                    // 0..2

    f32x4 acc[4];
#pragma unroll
    for (int j = 0; j < 4; j++) acc[j] = (f32x4){0.f,0.f,0.f,0.f};

    const bf16* abase = A + (size_t)(tok0 + c) * 768 + quad * 8;
    const bf16* bbase = Bt + (size_t)(s * 4) * 24 * 512 + lane * 8;
#pragma unroll 4
    for (int k0 = 0; k0 < 768; k0 += 32) {
        const int kch = k0 >> 5;
        bf16x8 af = *(const bf16x8*)(abase + k0);
#pragma unroll
        for (int nt = 0; nt < 4; nt++) {
            bf16x8 bfr = *(const bf16x8*)(bbase + (size_t)(nt * 24 + kch) * 512);
            acc[nt] = MFMA16(af, bfr, acc[nt]);
        }
    }

#pragma unroll
    for (int r = 0; r < 4; r++) {
        const int row = tok0 + quad*4 + r;
        const float* hg = hgate + (size_t)row * 20;
        float hres[16];
#pragma unroll
        for (int p = 0; p < 16; p++) hres[p] = hg[p];
        const float4 hp = *(const float4*)(hpost + (size_t)row * 4);
        const float hpi[4] = {hp.x, hp.y, hp.z, hp.w};
        const float* xrow = x + (size_t)row * ND;
        float* orow = out + (size_t)row * ND;
#pragma unroll
        for (int nt = 0; nt < 4; nt++) {
            const int col = s*64 + nt*16 + c;
            const float y = acc[nt][r] + x1[(size_t)row * 192 + col];
            float xv[4];
#pragma unroll
            for (int j = 0; j < 4; j++) xv[j] = xrow[j * 192 + col];
#pragma unroll
            for (int i = 0; i < 4; i++) {
                const float xr = hres[i*4+0]*xv[0] + hres[i*4+1]*xv[1]
                               + hres[i*4+2]*xv[2] + hres[i*4+3]*xv[3];
                orow[i * 192 + col] = xr + y * hpi[i];
            }
        }
    }
}

// ---------------------------------------------------------------------------
// V transpose: qkv[tok][384+h*64+d] -> vt[bh][d][seq]  (bf16)
// ---------------------------------------------------------------------------
__global__ __launch_bounds__(256) void vtrans_kernel(
    const bf16* __restrict__ qkv, bf16* __restrict__ vt)
{
    __shared__ bf16 t[64][72];
    const int tid = threadIdx.x;
    const int bh = blockIdx.y, b = bh / NH, h = bh % NH;
    const int s0 = blockIdx.x * 64;

#pragma unroll
    for (int i = 0; i < 2; i++) {
        const int chunk = tid + 256 * i;
        const int srow = chunk >> 3, g = chunk & 7;
        *(uint4*)&t[srow][g * 8] =
            *(const uint4*)(qkv + (size_t)(b * SEQ + s0 + srow) * 576 + 384 + h * 64 + g * 8);
    }
    __syncthreads();
#pragma unroll
    for (int i = 0; i < 2; i++) {
        const int chunk = tid + 256 * i;
        const int d = chunk >> 3, sg = chunk & 7;
        bf16x8 v;
#pragma unroll
        for (int j = 0; j < 8; j++) v[j] = t[sg * 8 + j][d];
        *(bf16x8*)(vt + ((size_t)bh * HD + d) * SEQ + s0 + sg * 8) = v;
    }
}

// ---------------------------------------------------------------------------
// MFMA flash attention: ONE WAVE per block (32 queries), grid (32, 96).
// exp2 softmax (log2e/8 folded into Wq), row-sum deferred to epilogue.
// ---------------------------------------------------------------------------
__global__ __launch_bounds__(64) void attn_mfma(
    const bf16* __restrict__ qkv, const bf16* __restrict__ vt,
    bf16* __restrict__ obuf)
{
    __shared__ bf16 Pw[32 * 64];
    const int lane = threadIdx.x;
    const int quad = lane >> 4, c = lane & 15;
    const int bh = blockIdx.y, b = bh / NH, h = bh % NH;
    const int q0 = blockIdx.x * 32;

    const bf16* kbase = qkv + (size_t)b * SEQ * 576 + 192 + h * 64;
    const bf16* vbase = vt + (size_t)bh * HD * SEQ;

    bf16x8 qf[2][2];
#pragma unroll
    for (int mt = 0; mt < 2; mt++)
#pragma unroll
        for (int ch = 0; ch < 2; ch++)
            qf[mt][ch] = *(const bf16x8*)(qkv + (size_t)(b * SEQ + q0 + mt*16 + c) * 576
                                              + h * 64 + ch * 32 + quad * 8);

    f32x4 of[2][4];
    float lst[2][4];
#pragma unroll
    for (int mt = 0; mt < 2; mt++)
#pragma unroll
        for (int r = 0; r < 4; r++) lst[mt][r] = 0.f;
#pragma unroll
    for (int mt = 0; mt < 2; mt++)
#pragma unroll
        for (int dt = 0; dt < 4; dt++) of[mt][dt] = (f32x4){0.f, 0.f, 0.f, 0.f};

#pragma unroll 1
    for (int kt = 0; kt < SEQ / 64; kt++) {
        f32x4 sf[2][4];
#pragma unroll
        for (int mt = 0; mt < 2; mt++)
#pragma unroll
            for (int nt = 0; nt < 4; nt++) sf[mt][nt] = (f32x4){0.f, 0.f, 0.f, 0.f};
#pragma unroll
        for (int ch = 0; ch < 2; ch++) {
            bf16x8 kf[4];
#pragma unroll
            for (int nt = 0; nt < 4; nt++)
                kf[nt] = *(const bf16x8*)(kbase + (size_t)(kt*64 + nt*16 + c) * 576
                                               + ch * 32 + quad * 8);
#pragma unroll
            for (int mt = 0; mt < 2; mt++)
#pragma unroll
                for (int nt = 0; nt < 4; nt++)
                    sf[mt][nt] = MFMA16(qf[mt][ch], kf[nt], sf[mt][nt]);
        }

#pragma unroll
        for (int mt = 0; mt < 2; mt++)
#pragma unroll
            for (int r = 0; r < 4; r++) {
                float rs = 0.f;
#pragma unroll
                for (int nt = 0; nt < 4; nt++) {
                    const float p = exp2f(sf[mt][nt][r]);
                    sf[mt][nt][r] = p;
                    rs += p;
                }
                lst[mt][r] += rs;
            }

#pragma unroll
        for (int mt = 0; mt < 2; mt++)
#pragma unroll
            for (int nt = 0; nt < 4; nt++)
#pragma unroll
                for (int r = 0; r < 4; r++) {
                    const int row = mt*16 + quad*4 + r;
                    const int col = nt*16 + c;
                    Pw[row*64 + (((col >> 3) ^ (row & 7)) * 8) + (col & 7)] =
                        (bf16)sf[mt][nt][r];
                }

#pragma unroll
        for (int ch = 0; ch < 2; ch++) {
            bf16x8 vf[4], pf[2];
#pragma unroll
            for (int dt = 0; dt < 4; dt++)
                vf[dt] = *(const bf16x8*)(vbase + (size_t)(dt*16 + c) * SEQ
                                               + kt*64 + ch*32 + quad*8);
#pragma unroll
            for (int mt = 0; mt < 2; mt++) {
                const int row = mt*16 + c;
                pf[mt] = *(const bf16x8*)(Pw + row*64 + (((ch*4 + quad) ^ (c & 7)) * 8));
            }
#pragma unroll
            for (int mt = 0; mt < 2; mt++)
#pragma unroll
                for (int dt = 0; dt < 4; dt++)
                    of[mt][dt] = MFMA16(pf[mt], vf[dt], of[mt][dt]);
        }
    }

#pragma unroll
    for (int mt = 0; mt < 2; mt++)
#pragma unroll
        for (int r = 0; r < 4; r++) {
            float s = lst[mt][r];
#pragma unroll
            for (int off = 1; off < 16; off <<= 1) s += __shfl_xor(s, off);
            const float inv = 1.0f / s;
            const size_t tok = (size_t)b * SEQ + q0 + mt*16 + quad*4 + r;
#pragma unroll
            for (int dt = 0; dt < 4; dt++)
                obuf[tok * DIM + h*64 + dt*16 + c] = (bf16)(of[mt][dt][r] * inv);
        }
}

// ---------------------------------------------------------------------------
extern "C" void kernel_launch(void* const* d_in, const int* in_sizes, int n_in,
                              void* d_out, int out_size, void* d_ws, size_t ws_size,
                              hipStream_t stream) {
    const float* x         = (const float*)d_in[0];
    const float* norm_w    = (const float*)d_in[1];
    const float* phi_pre   = (const float*)d_in[2];
    const float* phi_post  = (const float*)d_in[3];
    const float* phi_res   = (const float*)d_in[4];
    const float* b_pre     = (const float*)d_in[5];
    const float* b_post    = (const float*)d_in[6];
    const float* b_res     = (const float*)d_in[7];
    const float* alpha_pre = (const float*)d_in[8];
    const float* alpha_post= (const float*)d_in[9];
    const float* alpha_res = (const float*)d_in[10];
    const float* ln1_w     = (const float*)d_in[11];
    const float* ln1_b     = (const float*)d_in[12];
    const float* Wq        = (const float*)d_in[13];
    const float* Wk        = (const float*)d_in[14];
    const float* Wv        = (const float*)d_in[15];
    const float* Wo        = (const float*)d_in[16];
    const float* ln2_w     = (const float*)d_in[17];
    const float* ln2_b     = (const float*)d_in[18];
    const float* W1        = (const float*)d_in[19];
    const float* W2        = (const float*)d_in[20];

    float* out = (float*)d_out;
    float* ws  = (float*)d_ws;

    // ---- workspace carve (float units) — total ~130 MB ----
    const size_t TBf = (size_t)TOKENS * DIM;         // 6,291,456
    float* xin   = ws;                                // fp32 [TBf]
    float* x1    = ws + TBf;                          // fp32 [TBf]
    float* hpost = ws + 2 * TBf;                      // fp32 [131072]
    float* rinv  = hpost + 131072;                    // fp32 [32768]
    float* hgate = rinv + 32768;                      // fp32 [TOKENS*20] (alive to end!)
    bf16*  phiw  = (bf16*)(hgate + (size_t)TOKENS*20);// frag-linear [24576]
    bf16*  wqkv  = phiw + 24576;                      // [110592]
    bf16*  wot   = wqkv + 110592;                     // [36864]
    bf16*  w1t   = wot + 36864;                       // [147456]
    bf16*  w2t   = w1t + 147456;                      // [147456]
    float* regAC = (float*)(w2t + 147456);            // 12,582,912 floats
    bf16*  xb    = (bf16*)regAC;                      // [32768][768] (dead after mix)
    bf16*  qkv   = (bf16*)regAC;                      // [32768][576]
    bf16*  vt    = qkv + (size_t)TOKENS * 576;        // [96][64][1024]
    bf16*  gbuf  = (bf16*)regAC;                      // [32768][768] (after attn)
    float* regBD = regAC + 12582912;
    bf16*  h1    = (bf16*)regBD;                      // [32768][192]
    bf16*  obuf  = h1;                                // alias (h1 dead after QKV)
    bf16*  h2    = h1 + TBf;                          // [32768][192]
    float* dotsb = regBD + TBf / 2;                   // aliases h2 slot (dead before wo_ln)

    // 0. weight prep (frag-linear; 1/sqrt(64)*log2e folded into Wq)
    wprep_kernel<<<dim3(72, 1, 7), 256, 0, stream>>>(
        Wq, Wk, Wv, Wo, W1, W2, norm_w, phi_pre, phi_post, phi_res,
        wqkv, wot, w1t, w2t, phiw);

    // 1. gating pipeline
    prep_kernel<<<TOKENS, 64, 0, stream>>>(x, xb, rinv);
    dots_kernel<<<TOKENS / 64, 256, 0, stream>>>(xb, phiw, rinv, dotsb);
    sink_kernel<<<TOKENS / 256, 256, 0, stream>>>(
        dotsb, b_pre, b_post, b_res, alpha_pre, alpha_post, alpha_res, hgate, hpost);
    mix_kernel<<<TOKENS, 64, 0, stream>>>(xb, hgate, ln1_w, ln1_b, xin, h1);

    // 2. fused QKV projection (barrier-free, frag-linear B)
    gemm_bf<0, 192><<<dim3(576/64, TOKENS/256), 256, 0, stream>>>(h1, wqkv, qkv, 576);

    // 3. V transpose
    vtrans_kernel<<<dim3(SEQ/64, BATCH*NH), 256, 0, stream>>>(qkv, vt);

    // 4. attention -> obuf bf16 (1-wave blocks)
    attn_mfma<<<dim3(SEQ/32, BATCH*NH), 64, 0, stream>>>(qkv, vt, obuf);

    // 5. x1 = xin + obuf @ Wo, h2 = LN2(x1)  (fused)
    gemm_wo_ln<<<TOKENS/64, 256, 0, stream>>>(obuf, wot, xin, ln2_w, ln2_b, x1, h2);

    // 6. g = gelu(h2 @ W1) bf16 (barrier-free)
    gemm_bf<2, 192><<<dim3(768/64, TOKENS/256), 256, 0, stream>>>(h2, w1t, gbuf, 768);

    // 7. out = x_res + (x1 + g @ W2) * h_post  (fused, write-only out)
    gemm_w2_final<<<dim3(TOKENS/64, 3), 256, 0, stream>>>(
        gbuf, w2t, x1, x, hgate, hpost, out);
}